// Round 8
// baseline (1831.792 us; speedup 1.0000x reference)
//
#include <hip/hip_runtime.h>
#include <math.h>

#define H_DIM 4096
#define NHEAD 32
#define HD 128
#define FF_DIM 14336

typedef unsigned short u16;
typedef __attribute__((ext_vector_type(8))) short bf16x8;
typedef __attribute__((ext_vector_type(4))) float f32x4;

typedef const __attribute__((address_space(1))) void* gas_ptr;
typedef __attribute__((address_space(3))) void* las_ptr;

__device__ __forceinline__ void gload_lds16(const void* g, void* l) {
  __builtin_amdgcn_global_load_lds((gas_ptr)g, (las_ptr)l, 16, 0, 0);
}

__device__ __forceinline__ u16 f32_to_bf16(float f) {
  unsigned int u = __float_as_uint(f);
  u = (u + 0x7FFFu + ((u >> 16) & 1u)) >> 16;
  return (u16)u;
}
__device__ __forceinline__ float bf16_to_f32(u16 x) {
  return __uint_as_float(((unsigned int)x) << 16);
}

__device__ __forceinline__ void conv4(const float* __restrict__ in,
                                      u16* __restrict__ out, long i) {
  float4 v = reinterpret_cast<const float4*>(in)[i];
  ushort4 o;
  o.x = f32_to_bf16(v.x); o.y = f32_to_bf16(v.y);
  o.z = f32_to_bf16(v.z); o.w = f32_to_bf16(v.w);
  reinterpret_cast<ushort4*>(out)[i] = o;
}

// ---------------- fp32 -> bf16 weight conversion ----------------
__global__ void f2b_kernel(const float* __restrict__ in, u16* __restrict__ out, long n4) {
  long i = (long)blockIdx.x * blockDim.x + threadIdx.x;
  long stride = (long)gridDim.x * blockDim.x;
  for (; i < n4; i += stride) conv4(in, out, i);
}

// three equal-size weights -> one contiguous bf16 buffer
__global__ void f2b3_kernel(const float* __restrict__ a, const float* __restrict__ b,
                            const float* __restrict__ c, u16* __restrict__ out, long n4each) {
  long i = (long)blockIdx.x * blockDim.x + threadIdx.x;
  long st = (long)gridDim.x * blockDim.x;
  long tot = 3 * n4each;
  for (; i < tot; i += st) {
    const float* src; long j;
    if (i < n4each)            { src = a; j = i; }
    else if (i < 2 * n4each)   { src = b; j = i - n4each; }
    else                       { src = c; j = i - 2 * n4each; }
    float4 v = reinterpret_cast<const float4*>(src)[j];
    ushort4 o;
    o.x = f32_to_bf16(v.x); o.y = f32_to_bf16(v.y);
    o.z = f32_to_bf16(v.z); o.w = f32_to_bf16(v.w);
    reinterpret_cast<ushort4*>(out)[i] = o;
  }
}

// ---------------- bias concat (fp32) ----------------
__global__ void bias_concat_kernel(const float* __restrict__ a, const float* __restrict__ b,
                                   const float* __restrict__ c, float* __restrict__ out) {
  int i = blockIdx.x * blockDim.x + threadIdx.x;
  float v;
  if (i < 4096) v = a[i];
  else if (i < 8192) v = b[i - 4096];
  else v = c[i - 8192];
  out[i] = v;
}

// ---------------- RMSNorm (fp32 in, bf16 out) ----------------
__global__ void rmsnorm_kernel(const float* __restrict__ in, const float* __restrict__ w,
                               u16* __restrict__ out) {
  int row = blockIdx.x;
  int tid = threadIdx.x;
  const float4* x4 = reinterpret_cast<const float4*>(in + (size_t)row * H_DIM);
  float4 vv[4];
  float ss = 0.f;
#pragma unroll
  for (int it = 0; it < 4; ++it) {
    float4 v = x4[tid + it * 256];
    vv[it] = v;
    ss += v.x * v.x + v.y * v.y + v.z * v.z + v.w * v.w;
  }
#pragma unroll
  for (int off = 1; off < 64; off <<= 1) ss += __shfl_xor(ss, off);
  __shared__ float part[4];
  if ((tid & 63) == 0) part[tid >> 6] = ss;
  __syncthreads();
  float tot = part[0] + part[1] + part[2] + part[3];
  float rinv = rsqrtf(tot * (1.0f / H_DIM) + 1e-6f);
  const float4* w4 = reinterpret_cast<const float4*>(w);
  u16* orow = out + (size_t)row * H_DIM;
#pragma unroll
  for (int it = 0; it < 4; ++it) {
    float4 v = vv[it];
    float4 wv = w4[tid + it * 256];
    ushort4 o;
    o.x = f32_to_bf16(v.x * rinv * wv.x);
    o.y = f32_to_bf16(v.y * rinv * wv.y);
    o.z = f32_to_bf16(v.z * rinv * wv.z);
    o.w = f32_to_bf16(v.w * rinv * wv.w);
    reinterpret_cast<ushort4*>(orow)[tid + it * 256] = o;
  }
}

// ================= 256x256 8-phase bf16 GEMM (T1+T2+T3+T4+T5) =================
// Round-3/6 verified structure. CONV=true appends converter blocks
// (bid >= gemmBlocks) that soak tail-round idle CUs with fp32->bf16 work.
// GEMM occupancy is LDS-bound (1 block/CU), so the CONV branch's register
// inflation is harmless HERE — never put this branch in a VGPR-limited
// kernel (round-7 lesson: attn 84->172 VGPR, 3x slower).
enum { EPI_QKV = 0, EPI_O = 1, EPI_SILU = 2, EPI_MUL = 3, EPI_PART = 4 };

template <int EPI, bool SPLIT, bool CONV>
__global__ __launch_bounds__(512, 2) void gemm256(
    const u16* __restrict__ A, const u16* __restrict__ B, void* __restrict__ outp,
    const float* __restrict__ bias, const void* __restrict__ extra,
    int M, int N, int K, int kLen, int gemmBlocks,
    const float* __restrict__ c0in, u16* __restrict__ c0out, long c0n4,
    const float* __restrict__ c1in, u16* __restrict__ c1out, long c1n4) {
  if (CONV) {
    int cb = blockIdx.x - gemmBlocks;
    if (cb >= 0) {
      long nconv = gridDim.x - gemmBlocks;
      long base = (long)cb * 512 + threadIdx.x;
      long st = nconv * 512;
      for (long i = base; i < c0n4; i += st) conv4(c0in, c0out, i);
      if (c1in != nullptr)
        for (long i = base; i < c1n4; i += st) conv4(c1in, c1out, i);
      return;
    }
  }
  __shared__ __align__(16) u16 As[2][256 * 64];
  __shared__ __align__(16) u16 Bs[2][256 * 64];
  const int tid = threadIdx.x;
  const int wid = tid >> 6, lane = tid & 63;
  const int lg = lane >> 4, li = lane & 15;
  const int wr = (wid >> 2) << 7;  // 0 / 128
  const int wc = (wid & 3) << 6;   // 0,64,128,192

  const int nbm = M >> 8, nbn = N >> 8;
  const int nb = nbm * nbn;
  int wg = (blockIdx.x & 7) * (gemmBlocks >> 3) + (blockIdx.x >> 3);
  int s = 0;
  if (SPLIT) { s = wg / nb; wg -= s * nb; }
  const int m0 = (wg % nbm) << 8, n0 = (wg / nbm) << 8;
  const int kB = SPLIT ? s * kLen : 0;
  const int NT = kLen >> 6;

  // staging source pointers (pre-inverse-swizzled) + LDS dest offsets
  const int r8 = tid >> 3;
  const int sl = ((tid & 7) ^ (r8 & 7)) << 3;
  const u16* sA[2][2];
  const u16* sB[2][2];
  int ldo[2][2];
#pragma unroll
  for (int P = 0; P < 2; ++P)
#pragma unroll
    for (int h = 0; h < 2; ++h) {
      int lr = P * 128 + h * 64 + r8;
      int ra = (lr & 63) | ((lr >> 1) & 64) | ((lr << 1) & 128);
      int rb = (lr & 31) | ((lr & 96) << 1) | ((lr & 128) >> 2);
      sA[P][h] = A + (size_t)(m0 + ra) * K + kB + sl;
      sB[P][h] = B + (size_t)(n0 + rb) * K + kB + sl;
      ldo[P][h] = (P * 128 + h * 64 + (wid << 3)) << 6;
    }

  auto stageA = [&](int P, int d, int ko) {
#pragma unroll
    for (int h = 0; h < 2; ++h)
      gload_lds16(sA[P][h] + ko, (void*)(&As[d][ldo[P][h]]));
  };
  auto stageB = [&](int P, int d, int ko) {
#pragma unroll
    for (int h = 0; h < 2; ++h)
      gload_lds16(sB[P][h] + ko, (void*)(&Bs[d][ldo[P][h]]));
  };

  bf16x8 a[4][2], b[4][2];
  f32x4 acc[8][4] = {};
  const int s20 = (lg ^ (li & 7)) << 3;
  const int s21 = ((4 + lg) ^ (li & 7)) << 3;

  auto ldA = [&](int d, int set) {
#pragma unroll
    for (int i = 0; i < 4; ++i) {
      int g = wr + set * 64 + i * 16;
      int lb = (g & 63) | ((g >> 1) & 64) | ((g << 1) & 128);
      const u16* base = &As[d][(lb + li) << 6];
      a[i][0] = *reinterpret_cast<const bf16x8*>(base + s20);
      a[i][1] = *reinterpret_cast<const bf16x8*>(base + s21);
    }
  };
  auto ldB = [&](int d, int set) {
#pragma unroll
    for (int jj = 0; jj < 2; ++jj) {
      int hh = wc + (set * 2 + jj) * 16;
      int lb = ((hh & 32) << 2) | ((hh & 192) >> 1) | (hh & 31);
      const u16* base = &Bs[d][(lb + li) << 6];
      b[set * 2 + jj][0] = *reinterpret_cast<const bf16x8*>(base + s20);
      b[set * 2 + jj][1] = *reinterpret_cast<const bf16x8*>(base + s21);
    }
  };
  auto mm = [&](int iset, int jset) {
    __builtin_amdgcn_s_setprio(1);
#pragma unroll
    for (int i = 0; i < 4; ++i)
#pragma unroll
      for (int jj = 0; jj < 2; ++jj)
#pragma unroll
        for (int kk = 0; kk < 2; ++kk)
          acc[iset * 4 + i][jset * 2 + jj] = __builtin_amdgcn_mfma_f32_16x16x32_bf16(
              a[i][kk], b[jset * 2 + jj][kk], acc[iset * 4 + i][jset * 2 + jj], 0, 0, 0);
    __builtin_amdgcn_s_setprio(0);
  };

  // prologue: stage tiles 0 and 1
  stageA(0, 0, 0); stageB(0, 0, 0); stageB(1, 0, 0); stageA(1, 0, 0);
  if (NT > 1) {
    stageA(0, 1, 64); stageB(0, 1, 64); stageB(1, 1, 64); stageA(1, 1, 64);
    asm volatile("s_waitcnt vmcnt(8)" ::: "memory");
  } else {
    asm volatile("s_waitcnt vmcnt(0)" ::: "memory");
  }
  __builtin_amdgcn_s_barrier();

  for (int t = 0; t < NT; ++t) {
    int d = t & 1;
    bool pf = (t + 2) < NT;
    int ko = (t + 2) << 6;
    // ---- phase 1: reads A1+B1; MFMA quadrant (i0-3, j0-1)
    ldB(d, 0); ldA(d, 0);
    __builtin_amdgcn_s_barrier();
    mm(0, 0);
    __builtin_amdgcn_s_barrier();
    // ---- phase 2: reads B2; stage t+2.{A1,B1}; MFMA (i0-3, j2-3)
    ldB(d, 1);
    if (pf) { stageA(0, d, ko); stageB(0, d, ko); }
    __builtin_amdgcn_s_barrier();
    mm(0, 1);
    __builtin_amdgcn_s_barrier();
    // ---- phase 3: reads A2; stage t+2.B2; MFMA (i4-7, j0-1)
    ldA(d, 1);
    if (pf) stageB(1, d, ko);
    __builtin_amdgcn_s_barrier();
    mm(1, 0);
    __builtin_amdgcn_s_barrier();
    // ---- phase 4: stage t+2.A2; counted vmcnt; MFMA (i4-7, j2-3)
    if (pf) {
      stageA(1, d, ko);
      asm volatile("s_waitcnt vmcnt(6)" ::: "memory");
    } else {
      asm volatile("s_waitcnt vmcnt(0)" ::: "memory");
    }
    __builtin_amdgcn_s_barrier();
    mm(1, 1);
    __builtin_amdgcn_s_barrier();
  }

  // ---- epilogue
#pragma unroll
  for (int i = 0; i < 8; ++i) {
#pragma unroll
    for (int j = 0; j < 4; ++j) {
      int col = n0 + wc + j * 16 + li;
      float bv = 0.f;
      if (EPI == EPI_QKV || EPI == EPI_O) bv = bias[col];
      if (EPI == EPI_PART && bias != nullptr && s == 0) bv = bias[col];
#pragma unroll
      for (int r = 0; r < 4; ++r) {
        int row = m0 + wr + i * 16 + lg * 4 + r;
        float v = acc[i][j][r] + bv;
        size_t idx = (size_t)row * N + col;
        if (EPI == EPI_QKV) {
          ((u16*)outp)[idx] = f32_to_bf16(v);
        } else if (EPI == EPI_O) {
          const float* res = (const float*)extra;
          ((float*)outp)[idx] = res[idx] + v;
        } else if (EPI == EPI_SILU) {
          float sv = v / (1.f + __expf(-v));
          ((u16*)outp)[idx] = f32_to_bf16(sv);
        } else if (EPI == EPI_MUL) {
          const u16* sg = (const u16*)extra;
          ((u16*)outp)[idx] = f32_to_bf16(v * bf16_to_f32(sg[idx]));
        } else {  // EPI_PART: split-K partial, plain fp32 (bias folded at s==0)
          ((float*)outp)[(size_t)s * M * N + idx] = v;
        }
      }
    }
  }
}

// ---------------- split-K reduce + residual: out = res + p0 + p1 ----------------
__global__ void reduce_down(const float* __restrict__ p, const float* __restrict__ res,
                            float* __restrict__ out, long n4, long str4) {
  long i = (long)blockIdx.x * blockDim.x + threadIdx.x;
  long st = (long)gridDim.x * blockDim.x;
  for (; i < n4; i += st) {
    float4 h = reinterpret_cast<const float4*>(res)[i];
    float4 p0 = reinterpret_cast<const float4*>(p)[i];
    float4 p1 = reinterpret_cast<const float4*>(p)[i + str4];
    float4 o;
    o.x = h.x + p0.x + p1.x; o.y = h.y + p0.y + p1.y;
    o.z = h.z + p0.z + p1.z; o.w = h.w + p0.w + p1.w;
    reinterpret_cast<float4*>(out)[i] = o;
  }
}

// ---------------- bf16 transpose: in[S][ldin] (64-col slice) -> out[.][S] ----------------
__global__ void transpose_kernel(const u16* __restrict__ in, u16* __restrict__ out,
                                 int S, int ldin) {
  __shared__ __align__(16) u16 t[64][80];
  int sbT = S >> 6;
  int bs = blockIdx.x % sbT, bc = blockIdx.x / sbT;
  int s0 = bs << 6, c0 = bc << 6;
  int tid = threadIdx.x;
  int ir = tid >> 3;
  int jc = (tid & 7) * 8;
#pragma unroll
  for (int h = 0; h < 2; ++h) {
    int sr = ir + h * 32;
    uint4 v = *reinterpret_cast<const uint4*>(in + (size_t)(s0 + sr) * ldin + c0 + jc);
    *reinterpret_cast<uint4*>(&t[sr][jc]) = v;
  }
  __syncthreads();
  int d = tid >> 3;
  int ss = (tid & 7) * 8;
#pragma unroll
  for (int h = 0; h < 2; ++h) {
    int dd = d + h * 32;
    u16 tmp[8];
#pragma unroll
    for (int e = 0; e < 8; ++e) tmp[e] = t[ss + e][dd];
    *reinterpret_cast<uint4*>(out + (size_t)(c0 + dd) * S + s0 + ss) =
        *reinterpret_cast<const uint4*>(tmp);
  }
}

// ---------------- causal flash attention (CLEAN — no conv branch) ----------
// QBLK=32, KVBLK=64, balanced tile pairs, XOR-swizzled P-LDS. Keep this
// kernel free of any extra code paths: its occupancy is VGPR-limited.
__global__ __launch_bounds__(256) void attn_kernel(
    const u16* __restrict__ q, const u16* __restrict__ k,
    const u16* __restrict__ vt, u16* __restrict__ o, int S, int ldqk) {
  __shared__ __align__(16) u16 plds[4][32 * 64];
  int tid = threadIdx.x, wid = tid >> 6, lane = tid & 63;
  int lg = lane >> 4, li = lane & 15;
  int nwg = gridDim.x;
  int sbid = (blockIdx.x & 7) * (nwg >> 3) + (blockIdx.x >> 3);
  int task = sbid * 4 + wid;
  int pairs = S >> 6;
  int head = task / pairs;
  int pi = task - head * pairs;
  const float scale = 0.08838834764831845f;
  u16* pl = plds[wid];

  for (int tix = 0; tix < 2; ++tix) {
    int qt = tix ? ((S >> 5) - 1 - pi) : pi;
    int q0 = qt << 5;

    bf16x8 aq[2][4];
#pragma unroll
    for (int fi = 0; fi < 2; ++fi) {
      const u16* qrow = q + (size_t)(q0 + fi * 16 + li) * ldqk + head * HD + lg * 8;
#pragma unroll
      for (int ks = 0; ks < 4; ++ks)
        aq[fi][ks] = *reinterpret_cast<const bf16x8*>(qrow + ks * 32);
    }

    f32x4 oacc[2][8] = {};
    float m_run[2][4], l_run[2][4];
#pragma unroll
    for (int fi = 0; fi < 2; ++fi)
#pragma unroll
      for (int r = 0; r < 4; ++r) { m_run[fi][r] = -INFINITY; l_run[fi][r] = 0.f; }

    int nkb = ((q0 + 31) >> 6) + 1;
    for (int kb = 0; kb < nkb; ++kb) {
      int kvbase = kb << 6;
      f32x4 sacc[2][4] = {};
#pragma unroll
      for (int cf = 0; cf < 4; ++cf) {
        const u16* krow = k + (size_t)(kvbase + cf * 16 + li) * ldqk + head * HD + lg * 8;
#pragma unroll
        for (int ks = 0; ks < 4; ++ks) {
          bf16x8 bk = *reinterpret_cast<const bf16x8*>(krow + ks * 32);
          sacc[0][cf] = __builtin_amdgcn_mfma_f32_16x16x32_bf16(aq[0][ks], bk, sacc[0][cf], 0, 0, 0);
          sacc[1][cf] = __builtin_amdgcn_mfma_f32_16x16x32_bf16(aq[1][ks], bk, sacc[1][cf], 0, 0, 0);
        }
      }
      bool bnd = (kvbase + 63) > q0;
      float alpha[2][4];
#pragma unroll
      for (int fi = 0; fi < 2; ++fi) {
#pragma unroll
        for (int r = 0; r < 4; ++r) {
          int row = q0 + fi * 16 + lg * 4 + r;
#pragma unroll
          for (int cf = 0; cf < 4; ++cf) {
            float sv = sacc[fi][cf][r] * scale;
            if (bnd && (kvbase + cf * 16 + li) > row) sv = -INFINITY;
            sacc[fi][cf][r] = sv;
          }
          float mv = fmaxf(fmaxf(sacc[fi][0][r], sacc[fi][1][r]),
                           fmaxf(sacc[fi][2][r], sacc[fi][3][r]));
#pragma unroll
          for (int off = 1; off < 16; off <<= 1) mv = fmaxf(mv, __shfl_xor(mv, off));
          float mnew = fmaxf(m_run[fi][r], mv);
          alpha[fi][r] = __expf(m_run[fi][r] - mnew);
          m_run[fi][r] = mnew;
          float ps = 0.f;
#pragma unroll
          for (int cf = 0; cf < 4; ++cf) {
            float pv = __expf(sacc[fi][cf][r] - mnew);
            sacc[fi][cf][r] = pv;
            ps += pv;
          }
#pragma unroll
          for (int off = 1; off < 16; off <<= 1) ps += __shfl_xor(ps, off);
          l_run[fi][r] = l_run[fi][r] * alpha[fi][r] + ps;
        }
      }
#pragma unroll
      for (int fi = 0; fi < 2; ++fi)
#pragma unroll
        for (int df = 0; df < 8; ++df)
#pragma unroll
          for (int r = 0; r < 4; ++r) oacc[fi][df][r] *= alpha[fi][r];
#pragma unroll
      for (int fi = 0; fi < 2; ++fi)
#pragma unroll
        for (int cf = 0; cf < 4; ++cf)
#pragma unroll
          for (int r = 0; r < 4; ++r) {
            int row = fi * 16 + lg * 4 + r;
            int el = row * 64 + cf * 16 + li;
            pl[el ^ ((row & 7) << 3)] = f32_to_bf16(sacc[fi][cf][r]);
          }
      asm volatile("s_waitcnt lgkmcnt(0)" ::: "memory");
      __builtin_amdgcn_sched_barrier(0);
#pragma unroll
      for (int kk = 0; kk < 2; ++kk) {
        bf16x8 pa[2];
#pragma unroll
        for (int fi = 0; fi < 2; ++fi) {
          int row = fi * 16 + li;
          int el = row * 64 + kk * 32 + lg * 8;
          pa[fi] = *reinterpret_cast<const bf16x8*>(pl + (el ^ ((row & 7) << 3)));
        }
        const u16* vb = vt + kvbase + kk * 32 + lg * 8;
#pragma unroll
        for (int df = 0; df < 8; ++df) {
          bf16x8 bv = *reinterpret_cast<const bf16x8*>(vb + (size_t)(head * HD + df * 16 + li) * S);
          oacc[0][df] = __builtin_amdgcn_mfma_f32_16x16x32_bf16(pa[0], bv, oacc[0][df], 0, 0, 0);
          oacc[1][df] = __builtin_amdgcn_mfma_f32_16x16x32_bf16(pa[1], bv, oacc[1][df], 0, 0, 0);
        }
      }
    }
#pragma unroll
    for (int fi = 0; fi < 2; ++fi)
#pragma unroll
      for (int r = 0; r < 4; ++r) {
        float inv = 1.0f / l_run[fi][r];
        int row = q0 + fi * 16 + lg * 4 + r;
        u16* orow = o + (size_t)row * H_DIM + head * HD;
#pragma unroll
        for (int df = 0; df < 8; ++df)
          orow[df * 16 + li] = f32_to_bf16(oacc[fi][df][r] * inv);
      }
  }
}

extern "C" void kernel_launch(void* const* d_in, const int* in_sizes, int n_in,
                              void* d_out, int out_size, void* d_ws, size_t ws_size,
                              hipStream_t stream) {
  (void)n_in; (void)out_size;
  const float* hidden = (const float*)d_in[0];
  const float* wq = (const float*)d_in[2];
  const float* bq = (const float*)d_in[3];
  const float* wk = (const float*)d_in[4];
  const float* bk = (const float*)d_in[5];
  const float* wv = (const float*)d_in[6];
  const float* bv = (const float*)d_in[7];
  const float* wo = (const float*)d_in[8];
  const float* bo = (const float*)d_in[9];
  const float* wg = (const float*)d_in[10];
  const float* wu = (const float*)d_in[11];
  const float* wd = (const float*)d_in[12];
  const float* ln1 = (const float*)d_in[13];
  const float* ln2 = (const float*)d_in[14];
  float* out = (float*)d_out;

  int S = in_sizes[0] / H_DIM;  // 2048
  int NQKV = 3 * H_DIM;         // 12288

  char* ws = (char*)d_ws;
  size_t off = 0;
  auto alloc = [&](size_t bytes) {
    void* p = ws + off;
    off += (bytes + 255) & ~(size_t)255;
    return p;
  };
  // activations first (shared by both schedules)
  u16* xb   = (u16*)alloc((size_t)S * H_DIM * 2);
  u16* qkv  = (u16*)alloc((size_t)S * NQKV * 2);        // [S][12288]
  u16* vtb  = (u16*)alloc((size_t)S * H_DIM * 2);       // V^T [4096][S]
  u16* hat  = (u16*)alloc((size_t)S * H_DIM * 2);
  float* h1 = (float*)alloc((size_t)S * H_DIM * 4);
  u16* sg   = (u16*)alloc((size_t)S * FF_DIM * 2);
  u16* tb   = (u16*)alloc((size_t)S * FF_DIM * 2);
  float* bcat = (float*)alloc((size_t)NQKV * 4);
  // weight buffer 1: sized FF (117MB); holds QKV concat, later reused for wd
  u16* wbufQ = (u16*)alloc((size_t)FF_DIM * H_DIM * 2);
  size_t needSmall = off;
  // extra buffers for the overlapped schedule
  u16* wbufO = (u16*)alloc((size_t)H_DIM * H_DIM * 2);
  u16* wbufG = (u16*)alloc((size_t)FF_DIM * H_DIM * 2);
  u16* wbufU = (u16*)alloc((size_t)FF_DIM * H_DIM * 2);
  size_t needBig = off;
  if (needSmall > ws_size) return;
  bool big = (needBig <= ws_size);
  // split-K partials overlay qkv+vtb (dead by O-proj / down-proj time):
  // 2*S*H*4 = 67.11 MB == qkv(50.33)+vtb(16.78).
  float* pbuf = (float*)qkv;

  dim3 b256(256), b512(512);
  long nHH4 = (long)H_DIM * H_DIM / 4;
  long nFH4 = (long)FF_DIM * H_DIM / 4;
  int gQKV3 = (S / 256) * (NQKV / 256);      // 384
  int gO    = 2 * (S / 256) * (H_DIM / 256); // 256 (split-K=2)
  int gFF   = (S / 256) * (FF_DIM / 256);    // 448
  int gDW   = 2 * (S / 256) * (H_DIM / 256); // 256 (split-K=2)
  long n4HH = (long)S * H_DIM / 4;
  int gAttn = (NHEAD * (S / 64)) / 4;        // 256

  if (big) {
    // ---- overlapped schedule: conversions ride GEMM tail-round idle CUs only
    rmsnorm_kernel<<<S, b256, 0, stream>>>(hidden, ln1, xb);
    bias_concat_kernel<<<NQKV / 256, b256, 0, stream>>>(bq, bk, bv, bcat);
    f2b3_kernel<<<4096, b256, 0, stream>>>(wq, wk, wv, wbufQ, nHH4);
    // QKV GEMM (384 blocks, 1.5 rounds) + conv wo,wg on the 128-CU tail
    gemm256<EPI_QKV, false, true><<<gQKV3 + 128, b512, 0, stream>>>(
        xb, wbufQ, qkv, bcat, nullptr, S, NQKV, H_DIM, H_DIM, gQKV3,
        wo, wbufO, nHH4, wg, wbufG, nFH4);
    transpose_kernel<<<(S / 64) * (H_DIM / 64), b256, 0, stream>>>(qkv + 2 * H_DIM, vtb, S, NQKV);
    attn_kernel<<<gAttn, b256, 0, stream>>>(qkv, qkv + H_DIM, vtb, hat, S, NQKV);
    gemm256<EPI_PART, true, false><<<gO, b512, 0, stream>>>(
        hat, wbufO, pbuf, bo, nullptr, S, H_DIM, H_DIM, H_DIM / 2, gO,
        nullptr, nullptr, 0, nullptr, nullptr, 0);
    reduce_down<<<2048, b256, 0, stream>>>(pbuf, hidden, h1, n4HH, n4HH);

    rmsnorm_kernel<<<S, b256, 0, stream>>>(h1, ln2, xb);
    // gate (448 blocks, 1.75 rounds) + conv wu on the 64-CU tail
    gemm256<EPI_SILU, false, true><<<gFF + 64, b512, 0, stream>>>(
        xb, wbufG, sg, nullptr, nullptr, S, FF_DIM, H_DIM, H_DIM, gFF,
        wu, wbufU, nFH4, nullptr, nullptr, 0);
    // up + conv wd (into wbufQ, dead after QKV gemm)
    gemm256<EPI_MUL, false, true><<<gFF + 64, b512, 0, stream>>>(
        xb, wbufU, tb, nullptr, sg, S, FF_DIM, H_DIM, H_DIM, gFF,
        wd, wbufQ, nFH4, nullptr, nullptr, 0);
    gemm256<EPI_PART, true, false><<<gDW, b512, 0, stream>>>(
        tb, wbufQ, pbuf, nullptr, nullptr, S, H_DIM, FF_DIM, FF_DIM / 2, gDW,
        nullptr, nullptr, 0, nullptr, nullptr, 0);
    reduce_down<<<2048, b256, 0, stream>>>(pbuf, h1, out, n4HH, n4HH);
  } else {
    // ---- fallback: round-6 proven serial schedule (shared weight buffer)
    u16* wbuf = wbufQ;
    rmsnorm_kernel<<<S, b256, 0, stream>>>(hidden, ln1, xb);
    bias_concat_kernel<<<NQKV / 256, b256, 0, stream>>>(bq, bk, bv, bcat);
    f2b3_kernel<<<4096, b256, 0, stream>>>(wq, wk, wv, wbuf, nHH4);
    gemm256<EPI_QKV, false, false><<<gQKV3, b512, 0, stream>>>(
        xb, wbuf, qkv, bcat, nullptr, S, NQKV, H_DIM, H_DIM, gQKV3,
        nullptr, nullptr, 0, nullptr, nullptr, 0);
    transpose_kernel<<<(S / 64) * (H_DIM / 64), b256, 0, stream>>>(qkv + 2 * H_DIM, vtb, S, NQKV);
    attn_kernel<<<gAttn, b256, 0, stream>>>(qkv, qkv + H_DIM, vtb, hat, S, NQKV);
    f2b_kernel<<<4096, b256, 0, stream>>>(wo, wbuf, nHH4);
    gemm256<EPI_PART, true, false><<<gO, b512, 0, stream>>>(
        hat, wbuf, pbuf, bo, nullptr, S, H_DIM, H_DIM, H_DIM / 2, gO,
        nullptr, nullptr, 0, nullptr, nullptr, 0);
    reduce_down<<<2048, b256, 0, stream>>>(pbuf, hidden, h1, n4HH, n4HH);

    rmsnorm_kernel<<<S, b256, 0, stream>>>(h1, ln2, xb);
    f2b_kernel<<<4096, b256, 0, stream>>>(wg, wbuf, nFH4);
    gemm256<EPI_SILU, false, false><<<gFF, b512, 0, stream>>>(
        xb, wbuf, sg, nullptr, nullptr, S, FF_DIM, H_DIM, H_DIM, gFF,
        nullptr, nullptr, 0, nullptr, nullptr, 0);
    f2b_kernel<<<4096, b256, 0, stream>>>(wu, wbuf, nFH4);
    gemm256<EPI_MUL, false, false><<<gFF, b512, 0, stream>>>(
        xb, wbuf, tb, nullptr, sg, S, FF_DIM, H_DIM, H_DIM, gFF,
        nullptr, nullptr, 0, nullptr, nullptr, 0);
    f2b_kernel<<<4096, b256, 0, stream>>>(wd, wbuf, nFH4);
    gemm256<EPI_PART, true, false><<<gDW, b512, 0, stream>>>(
        tb, wbuf, pbuf, nullptr, nullptr, S, H_DIM, FF_DIM, FF_DIM / 2, gDW,
        nullptr, nullptr, 0, nullptr, nullptr, 0);
    reduce_down<<<2048, b256, 0, stream>>>(pbuf, h1, out, n4HH, n4HH);
  }
}

// Round 9
// 1678.971 us; speedup vs baseline: 1.0910x; 1.0910x over previous
//
#include <hip/hip_runtime.h>
#include <math.h>

#define H_DIM 4096
#define NHEAD 32
#define HD 128
#define FF_DIM 14336

typedef unsigned short u16;
typedef __attribute__((ext_vector_type(8))) short bf16x8;
typedef __attribute__((ext_vector_type(4))) float f32x4;

typedef const __attribute__((address_space(1))) void* gas_ptr;
typedef __attribute__((address_space(3))) void* las_ptr;

__device__ __forceinline__ void gload_lds16(const void* g, void* l) {
  __builtin_amdgcn_global_load_lds((gas_ptr)g, (las_ptr)l, 16, 0, 0);
}

__device__ __forceinline__ u16 f32_to_bf16(float f) {
  unsigned int u = __float_as_uint(f);
  u = (u + 0x7FFFu + ((u >> 16) & 1u)) >> 16;
  return (u16)u;
}
__device__ __forceinline__ float bf16_to_f32(u16 x) {
  return __uint_as_float(((unsigned int)x) << 16);
}

__device__ __forceinline__ void conv4(const float* __restrict__ in,
                                      u16* __restrict__ out, long i) {
  float4 v = reinterpret_cast<const float4*>(in)[i];
  ushort4 o;
  o.x = f32_to_bf16(v.x); o.y = f32_to_bf16(v.y);
  o.z = f32_to_bf16(v.z); o.w = f32_to_bf16(v.w);
  reinterpret_cast<ushort4*>(out)[i] = o;
}

// ---------------- fp32 -> bf16 weight conversion ----------------
__global__ void f2b_kernel(const float* __restrict__ in, u16* __restrict__ out, long n4) {
  long i = (long)blockIdx.x * blockDim.x + threadIdx.x;
  long stride = (long)gridDim.x * blockDim.x;
  for (; i < n4; i += stride) conv4(in, out, i);
}

// three equal-size weights -> one contiguous bf16 buffer
__global__ void f2b3_kernel(const float* __restrict__ a, const float* __restrict__ b,
                            const float* __restrict__ c, u16* __restrict__ out, long n4each) {
  long i = (long)blockIdx.x * blockDim.x + threadIdx.x;
  long st = (long)gridDim.x * blockDim.x;
  long tot = 3 * n4each;
  for (; i < tot; i += st) {
    const float* src; long j;
    if (i < n4each)            { src = a; j = i; }
    else if (i < 2 * n4each)   { src = b; j = i - n4each; }
    else                       { src = c; j = i - 2 * n4each; }
    float4 v = reinterpret_cast<const float4*>(src)[j];
    ushort4 o;
    o.x = f32_to_bf16(v.x); o.y = f32_to_bf16(v.y);
    o.z = f32_to_bf16(v.z); o.w = f32_to_bf16(v.w);
    reinterpret_cast<ushort4*>(out)[i] = o;
  }
}

// ---------------- bias concat (fp32) ----------------
__global__ void bias_concat_kernel(const float* __restrict__ a, const float* __restrict__ b,
                                   const float* __restrict__ c, float* __restrict__ out) {
  int i = blockIdx.x * blockDim.x + threadIdx.x;
  float v;
  if (i < 4096) v = a[i];
  else if (i < 8192) v = b[i - 4096];
  else v = c[i - 8192];
  out[i] = v;
}

// ---------------- RMSNorm (fp32 in, bf16 out) ----------------
__global__ void rmsnorm_kernel(const float* __restrict__ in, const float* __restrict__ w,
                               u16* __restrict__ out) {
  int row = blockIdx.x;
  int tid = threadIdx.x;
  const float4* x4 = reinterpret_cast<const float4*>(in + (size_t)row * H_DIM);
  float4 vv[4];
  float ss = 0.f;
#pragma unroll
  for (int it = 0; it < 4; ++it) {
    float4 v = x4[tid + it * 256];
    vv[it] = v;
    ss += v.x * v.x + v.y * v.y + v.z * v.z + v.w * v.w;
  }
#pragma unroll
  for (int off = 1; off < 64; off <<= 1) ss += __shfl_xor(ss, off);
  __shared__ float part[4];
  if ((tid & 63) == 0) part[tid >> 6] = ss;
  __syncthreads();
  float tot = part[0] + part[1] + part[2] + part[3];
  float rinv = rsqrtf(tot * (1.0f / H_DIM) + 1e-6f);
  const float4* w4 = reinterpret_cast<const float4*>(w);
  u16* orow = out + (size_t)row * H_DIM;
#pragma unroll
  for (int it = 0; it < 4; ++it) {
    float4 v = vv[it];
    float4 wv = w4[tid + it * 256];
    ushort4 o;
    o.x = f32_to_bf16(v.x * rinv * wv.x);
    o.y = f32_to_bf16(v.y * rinv * wv.y);
    o.z = f32_to_bf16(v.z * rinv * wv.z);
    o.w = f32_to_bf16(v.w * rinv * wv.w);
    reinterpret_cast<ushort4*>(orow)[tid + it * 256] = o;
  }
}

// ================= 256x256 8-phase bf16 GEMM (T1+T2+T3+T4+T5) =================
// Round-6 proven structure + frag-prefetch hoist: all ds_reads issue one phase
// early (B-set1 in P1 into its own regs; A-set1 in P2 into a2[4][2]) so phases
// 3/4 are ds-free and the compiler's counted lgkmcnt hides each ds-drain under
// the previous MFMA cluster. DMA stage placement / barriers / vmcnt identical
// to round 6 (hazard windows unchanged).
// Round-5 lesson: unified VGPR budget 256/wave; a2 adds 32 -> ~150, safe.
// Round-8 lesson: do NOT co-schedule converter blocks with this kernel —
// their streams evict B-panels from L2 (FETCH +115MB, dur +40%).
enum { EPI_QKV = 0, EPI_O = 1, EPI_SILU = 2, EPI_MUL = 3, EPI_PART = 4 };

template <int EPI, bool SPLIT>
__global__ __launch_bounds__(512, 2) void gemm256(
    const u16* __restrict__ A, const u16* __restrict__ B, void* __restrict__ outp,
    const float* __restrict__ bias, const void* __restrict__ extra,
    int M, int N, int K, int kLen) {
  __shared__ __align__(16) u16 As[2][256 * 64];
  __shared__ __align__(16) u16 Bs[2][256 * 64];
  const int tid = threadIdx.x;
  const int wid = tid >> 6, lane = tid & 63;
  const int lg = lane >> 4, li = lane & 15;
  const int wr = (wid >> 2) << 7;  // 0 / 128
  const int wc = (wid & 3) << 6;   // 0,64,128,192

  const int nbm = M >> 8, nbn = N >> 8;
  const int nb = nbm * nbn;
  int wg = (blockIdx.x & 7) * (gridDim.x >> 3) + (blockIdx.x >> 3);
  int s = 0;
  if (SPLIT) { s = wg / nb; wg -= s * nb; }
  const int m0 = (wg % nbm) << 8, n0 = (wg / nbm) << 8;
  const int kB = SPLIT ? s * kLen : 0;
  const int NT = kLen >> 6;

  // staging source pointers (pre-inverse-swizzled) + LDS dest offsets
  const int r8 = tid >> 3;
  const int sl = ((tid & 7) ^ (r8 & 7)) << 3;
  const u16* sA[2][2];
  const u16* sB[2][2];
  int ldo[2][2];
#pragma unroll
  for (int P = 0; P < 2; ++P)
#pragma unroll
    for (int h = 0; h < 2; ++h) {
      int lr = P * 128 + h * 64 + r8;
      int ra = (lr & 63) | ((lr >> 1) & 64) | ((lr << 1) & 128);
      int rb = (lr & 31) | ((lr & 96) << 1) | ((lr & 128) >> 2);
      sA[P][h] = A + (size_t)(m0 + ra) * K + kB + sl;
      sB[P][h] = B + (size_t)(n0 + rb) * K + kB + sl;
      ldo[P][h] = (P * 128 + h * 64 + (wid << 3)) << 6;
    }

  auto stageA = [&](int P, int d, int ko) {
#pragma unroll
    for (int h = 0; h < 2; ++h)
      gload_lds16(sA[P][h] + ko, (void*)(&As[d][ldo[P][h]]));
  };
  auto stageB = [&](int P, int d, int ko) {
#pragma unroll
    for (int h = 0; h < 2; ++h)
      gload_lds16(sB[P][h] + ko, (void*)(&Bs[d][ldo[P][h]]));
  };

  bf16x8 a[4][2], a2[4][2], b[4][2];
  f32x4 acc[8][4] = {};
  const int s20 = (lg ^ (li & 7)) << 3;
  const int s21 = ((4 + lg) ^ (li & 7)) << 3;

  auto ldA = [&](int d, int set, bf16x8 (&dst)[4][2]) {
#pragma unroll
    for (int i = 0; i < 4; ++i) {
      int g = wr + set * 64 + i * 16;
      int lb = (g & 63) | ((g >> 1) & 64) | ((g << 1) & 128);
      const u16* base = &As[d][(lb + li) << 6];
      dst[i][0] = *reinterpret_cast<const bf16x8*>(base + s20);
      dst[i][1] = *reinterpret_cast<const bf16x8*>(base + s21);
    }
  };
  auto ldB = [&](int d, int set) {
#pragma unroll
    for (int jj = 0; jj < 2; ++jj) {
      int hh = wc + (set * 2 + jj) * 16;
      int lb = ((hh & 32) << 2) | ((hh & 192) >> 1) | (hh & 31);
      const u16* base = &Bs[d][(lb + li) << 6];
      b[set * 2 + jj][0] = *reinterpret_cast<const bf16x8*>(base + s20);
      b[set * 2 + jj][1] = *reinterpret_cast<const bf16x8*>(base + s21);
    }
  };
  auto mm = [&](bf16x8 (&aa)[4][2], int iset, int jset) {
    __builtin_amdgcn_s_setprio(1);
#pragma unroll
    for (int i = 0; i < 4; ++i)
#pragma unroll
      for (int jj = 0; jj < 2; ++jj)
#pragma unroll
        for (int kk = 0; kk < 2; ++kk)
          acc[iset * 4 + i][jset * 2 + jj] = __builtin_amdgcn_mfma_f32_16x16x32_bf16(
              aa[i][kk], b[jset * 2 + jj][kk], acc[iset * 4 + i][jset * 2 + jj], 0, 0, 0);
    __builtin_amdgcn_s_setprio(0);
  };

  // prologue: stage tiles 0 and 1
  stageA(0, 0, 0); stageB(0, 0, 0); stageB(1, 0, 0); stageA(1, 0, 0);
  if (NT > 1) {
    stageA(0, 1, 64); stageB(0, 1, 64); stageB(1, 1, 64); stageA(1, 1, 64);
    asm volatile("s_waitcnt vmcnt(8)" ::: "memory");
  } else {
    asm volatile("s_waitcnt vmcnt(0)" ::: "memory");
  }
  __builtin_amdgcn_s_barrier();

  for (int t = 0; t < NT; ++t) {
    int d = t & 1;
    bool pf = (t + 2) < NT;
    int ko = (t + 2) << 6;
    // ---- phase 1: read frags A1,B1 AND B2 (hoisted); MFMA (i0-3, j0-1)
    ldB(d, 0); ldA(d, 0, a); ldB(d, 1);
    __builtin_amdgcn_s_barrier();
    mm(a, 0, 0);
    __builtin_amdgcn_s_barrier();
    // ---- phase 2: read A2 frags -> a2 (hoisted); stage t+2.{A1,B1}; MFMA (i0-3, j2-3)
    ldA(d, 1, a2);
    if (pf) { stageA(0, d, ko); stageB(0, d, ko); }
    __builtin_amdgcn_s_barrier();
    mm(a, 0, 1);
    __builtin_amdgcn_s_barrier();
    // ---- phase 3: ds-free; stage t+2.B2; MFMA (i4-7, j0-1)
    if (pf) stageB(1, d, ko);
    __builtin_amdgcn_s_barrier();
    mm(a2, 1, 0);
    __builtin_amdgcn_s_barrier();
    // ---- phase 4: ds-free; stage t+2.A2; counted vmcnt; MFMA (i4-7, j2-3)
    if (pf) {
      stageA(1, d, ko);
      asm volatile("s_waitcnt vmcnt(6)" ::: "memory");
    } else {
      asm volatile("s_waitcnt vmcnt(0)" ::: "memory");
    }
    __builtin_amdgcn_s_barrier();
    mm(a2, 1, 1);
    __builtin_amdgcn_s_barrier();
  }

  // ---- epilogue
#pragma unroll
  for (int i = 0; i < 8; ++i) {
#pragma unroll
    for (int j = 0; j < 4; ++j) {
      int col = n0 + wc + j * 16 + li;
      float bv = 0.f;
      if (EPI == EPI_QKV || EPI == EPI_O) bv = bias[col];
      if (EPI == EPI_PART && bias != nullptr && s == 0) bv = bias[col];
#pragma unroll
      for (int r = 0; r < 4; ++r) {
        int row = m0 + wr + i * 16 + lg * 4 + r;
        float v = acc[i][j][r] + bv;
        size_t idx = (size_t)row * N + col;
        if (EPI == EPI_QKV) {
          ((u16*)outp)[idx] = f32_to_bf16(v);
        } else if (EPI == EPI_O) {
          const float* res = (const float*)extra;
          ((float*)outp)[idx] = res[idx] + v;
        } else if (EPI == EPI_SILU) {
          float sv = v / (1.f + __expf(-v));
          ((u16*)outp)[idx] = f32_to_bf16(sv);
        } else if (EPI == EPI_MUL) {
          const u16* sg = (const u16*)extra;
          ((u16*)outp)[idx] = f32_to_bf16(v * bf16_to_f32(sg[idx]));
        } else {  // EPI_PART: split-K partial, plain fp32 (bias folded at s==0)
          ((float*)outp)[(size_t)s * M * N + idx] = v;
        }
      }
    }
  }
}

// ---------------- split-K reduce + residual: out = res + p0 + p1 ----------------
__global__ void reduce_down(const float* __restrict__ p, const float* __restrict__ res,
                            float* __restrict__ out, long n4, long str4) {
  long i = (long)blockIdx.x * blockDim.x + threadIdx.x;
  long st = (long)gridDim.x * blockDim.x;
  for (; i < n4; i += st) {
    float4 h = reinterpret_cast<const float4*>(res)[i];
    float4 p0 = reinterpret_cast<const float4*>(p)[i];
    float4 p1 = reinterpret_cast<const float4*>(p)[i + str4];
    float4 o;
    o.x = h.x + p0.x + p1.x; o.y = h.y + p0.y + p1.y;
    o.z = h.z + p0.z + p1.z; o.w = h.w + p0.w + p1.w;
    reinterpret_cast<float4*>(out)[i] = o;
  }
}

// ---------------- bf16 transpose: in[S][ldin] (64-col slice) -> out[.][S] ----------------
__global__ void transpose_kernel(const u16* __restrict__ in, u16* __restrict__ out,
                                 int S, int ldin) {
  __shared__ __align__(16) u16 t[64][80];
  int sbT = S >> 6;
  int bs = blockIdx.x % sbT, bc = blockIdx.x / sbT;
  int s0 = bs << 6, c0 = bc << 6;
  int tid = threadIdx.x;
  int ir = tid >> 3;
  int jc = (tid & 7) * 8;
#pragma unroll
  for (int h = 0; h < 2; ++h) {
    int sr = ir + h * 32;
    uint4 v = *reinterpret_cast<const uint4*>(in + (size_t)(s0 + sr) * ldin + c0 + jc);
    *reinterpret_cast<uint4*>(&t[sr][jc]) = v;
  }
  __syncthreads();
  int d = tid >> 3;
  int ss = (tid & 7) * 8;
#pragma unroll
  for (int h = 0; h < 2; ++h) {
    int dd = d + h * 32;
    u16 tmp[8];
#pragma unroll
    for (int e = 0; e < 8; ++e) tmp[e] = t[ss + e][dd];
    *reinterpret_cast<uint4*>(out + (size_t)(c0 + dd) * S + s0 + ss) =
        *reinterpret_cast<const uint4*>(tmp);
  }
}

// ---------------- causal flash attention (CLEAN — no extra branches) --------
// QBLK=32, KVBLK=64, balanced tile pairs, XOR-swizzled P-LDS. VGPR-limited
// occupancy: keep this kernel single-purpose (round-7 lesson).
__global__ __launch_bounds__(256) void attn_kernel(
    const u16* __restrict__ q, const u16* __restrict__ k,
    const u16* __restrict__ vt, u16* __restrict__ o, int S, int ldqk) {
  __shared__ __align__(16) u16 plds[4][32 * 64];
  int tid = threadIdx.x, wid = tid >> 6, lane = tid & 63;
  int lg = lane >> 4, li = lane & 15;
  int nwg = gridDim.x;
  int sbid = (blockIdx.x & 7) * (nwg >> 3) + (blockIdx.x >> 3);
  int task = sbid * 4 + wid;
  int pairs = S >> 6;
  int head = task / pairs;
  int pi = task - head * pairs;
  const float scale = 0.08838834764831845f;
  u16* pl = plds[wid];

  for (int tix = 0; tix < 2; ++tix) {
    int qt = tix ? ((S >> 5) - 1 - pi) : pi;
    int q0 = qt << 5;

    bf16x8 aq[2][4];
#pragma unroll
    for (int fi = 0; fi < 2; ++fi) {
      const u16* qrow = q + (size_t)(q0 + fi * 16 + li) * ldqk + head * HD + lg * 8;
#pragma unroll
      for (int ks = 0; ks < 4; ++ks)
        aq[fi][ks] = *reinterpret_cast<const bf16x8*>(qrow + ks * 32);
    }

    f32x4 oacc[2][8] = {};
    float m_run[2][4], l_run[2][4];
#pragma unroll
    for (int fi = 0; fi < 2; ++fi)
#pragma unroll
      for (int r = 0; r < 4; ++r) { m_run[fi][r] = -INFINITY; l_run[fi][r] = 0.f; }

    int nkb = ((q0 + 31) >> 6) + 1;
    for (int kb = 0; kb < nkb; ++kb) {
      int kvbase = kb << 6;
      f32x4 sacc[2][4] = {};
#pragma unroll
      for (int cf = 0; cf < 4; ++cf) {
        const u16* krow = k + (size_t)(kvbase + cf * 16 + li) * ldqk + head * HD + lg * 8;
#pragma unroll
        for (int ks = 0; ks < 4; ++ks) {
          bf16x8 bk = *reinterpret_cast<const bf16x8*>(krow + ks * 32);
          sacc[0][cf] = __builtin_amdgcn_mfma_f32_16x16x32_bf16(aq[0][ks], bk, sacc[0][cf], 0, 0, 0);
          sacc[1][cf] = __builtin_amdgcn_mfma_f32_16x16x32_bf16(aq[1][ks], bk, sacc[1][cf], 0, 0, 0);
        }
      }
      bool bnd = (kvbase + 63) > q0;
      float alpha[2][4];
#pragma unroll
      for (int fi = 0; fi < 2; ++fi) {
#pragma unroll
        for (int r = 0; r < 4; ++r) {
          int row = q0 + fi * 16 + lg * 4 + r;
#pragma unroll
          for (int cf = 0; cf < 4; ++cf) {
            float sv = sacc[fi][cf][r] * scale;
            if (bnd && (kvbase + cf * 16 + li) > row) sv = -INFINITY;
            sacc[fi][cf][r] = sv;
          }
          float mv = fmaxf(fmaxf(sacc[fi][0][r], sacc[fi][1][r]),
                           fmaxf(sacc[fi][2][r], sacc[fi][3][r]));
#pragma unroll
          for (int off = 1; off < 16; off <<= 1) mv = fmaxf(mv, __shfl_xor(mv, off));
          float mnew = fmaxf(m_run[fi][r], mv);
          alpha[fi][r] = __expf(m_run[fi][r] - mnew);
          m_run[fi][r] = mnew;
          float ps = 0.f;
#pragma unroll
          for (int cf = 0; cf < 4; ++cf) {
            float pv = __expf(sacc[fi][cf][r] - mnew);
            sacc[fi][cf][r] = pv;
            ps += pv;
          }
#pragma unroll
          for (int off = 1; off < 16; off <<= 1) ps += __shfl_xor(ps, off);
          l_run[fi][r] = l_run[fi][r] * alpha[fi][r] + ps;
        }
      }
#pragma unroll
      for (int fi = 0; fi < 2; ++fi)
#pragma unroll
        for (int df = 0; df < 8; ++df)
#pragma unroll
          for (int r = 0; r < 4; ++r) oacc[fi][df][r] *= alpha[fi][r];
#pragma unroll
      for (int fi = 0; fi < 2; ++fi)
#pragma unroll
        for (int cf = 0; cf < 4; ++cf)
#pragma unroll
          for (int r = 0; r < 4; ++r) {
            int row = fi * 16 + lg * 4 + r;
            int el = row * 64 + cf * 16 + li;
            pl[el ^ ((row & 7) << 3)] = f32_to_bf16(sacc[fi][cf][r]);
          }
      asm volatile("s_waitcnt lgkmcnt(0)" ::: "memory");
      __builtin_amdgcn_sched_barrier(0);
#pragma unroll
      for (int kk = 0; kk < 2; ++kk) {
        bf16x8 pa[2];
#pragma unroll
        for (int fi = 0; fi < 2; ++fi) {
          int row = fi * 16 + li;
          int el = row * 64 + kk * 32 + lg * 8;
          pa[fi] = *reinterpret_cast<const bf16x8*>(pl + (el ^ ((row & 7) << 3)));
        }
        const u16* vb = vt + kvbase + kk * 32 + lg * 8;
#pragma unroll
        for (int df = 0; df < 8; ++df) {
          bf16x8 bv = *reinterpret_cast<const bf16x8*>(vb + (size_t)(head * HD + df * 16 + li) * S);
          oacc[0][df] = __builtin_amdgcn_mfma_f32_16x16x32_bf16(pa[0], bv, oacc[0][df], 0, 0, 0);
          oacc[1][df] = __builtin_amdgcn_mfma_f32_16x16x32_bf16(pa[1], bv, oacc[1][df], 0, 0, 0);
        }
      }
    }
#pragma unroll
    for (int fi = 0; fi < 2; ++fi)
#pragma unroll
      for (int r = 0; r < 4; ++r) {
        float inv = 1.0f / l_run[fi][r];
        int row = q0 + fi * 16 + lg * 4 + r;
        u16* orow = o + (size_t)row * H_DIM + head * HD;
#pragma unroll
        for (int df = 0; df < 8; ++df)
          orow[df * 16 + li] = f32_to_bf16(oacc[fi][df][r] * inv);
      }
  }
}

extern "C" void kernel_launch(void* const* d_in, const int* in_sizes, int n_in,
                              void* d_out, int out_size, void* d_ws, size_t ws_size,
                              hipStream_t stream) {
  (void)n_in; (void)out_size;
  const float* hidden = (const float*)d_in[0];
  const float* wq = (const float*)d_in[2];
  const float* bq = (const float*)d_in[3];
  const float* wk = (const float*)d_in[4];
  const float* bk = (const float*)d_in[5];
  const float* wv = (const float*)d_in[6];
  const float* bv = (const float*)d_in[7];
  const float* wo = (const float*)d_in[8];
  const float* bo = (const float*)d_in[9];
  const float* wg = (const float*)d_in[10];
  const float* wu = (const float*)d_in[11];
  const float* wd = (const float*)d_in[12];
  const float* ln1 = (const float*)d_in[13];
  const float* ln2 = (const float*)d_in[14];
  float* out = (float*)d_out;

  int S = in_sizes[0] / H_DIM;  // 2048
  int NQKV = 3 * H_DIM;         // 12288

  char* ws = (char*)d_ws;
  size_t off = 0;
  auto alloc = [&](size_t bytes) {
    void* p = ws + off;
    off += (bytes + 255) & ~(size_t)255;
    return p;
  };
  u16* wbuf = (u16*)alloc((size_t)FF_DIM * H_DIM * 2);  // shared weight bf16 buffer
  u16* xb   = (u16*)alloc((size_t)S * H_DIM * 2);
  u16* qkv  = (u16*)alloc((size_t)S * NQKV * 2);        // [S][12288]
  u16* vtb  = (u16*)alloc((size_t)S * H_DIM * 2);       // V^T [4096][S]
  u16* hat  = (u16*)alloc((size_t)S * H_DIM * 2);
  float* h1 = (float*)alloc((size_t)S * H_DIM * 4);
  u16* sg   = (u16*)alloc((size_t)S * FF_DIM * 2);
  u16* tb   = (u16*)alloc((size_t)S * FF_DIM * 2);
  float* bcat = (float*)alloc((size_t)NQKV * 4);
  if (off > ws_size) return;
  // split-K partials overlay qkv+vtb (both dead by O-proj / down-proj time):
  // need 2*S*H*4 = 67.11 MB; qkv(50.33) + vtb(16.78) = 67.11 MB exactly.
  float* pbuf = (float*)qkv;

  dim3 b256(256), b512(512);
  long nHH4 = (long)H_DIM * H_DIM / 4;
  long nFH4 = (long)FF_DIM * H_DIM / 4;
  int gQKV3 = (S / 256) * (NQKV / 256);      // 384
  int gO    = 2 * (S / 256) * (H_DIM / 256); // 256 (split-K=2)
  int gFF   = (S / 256) * (FF_DIM / 256);    // 448
  int gDW   = 2 * (S / 256) * (H_DIM / 256); // 256 (split-K=2)
  long n4HH = (long)S * H_DIM / 4;
  int gAttn = (NHEAD * (S / 64)) / 4;        // 256

  // attention block
  rmsnorm_kernel<<<S, b256, 0, stream>>>(hidden, ln1, xb);
  bias_concat_kernel<<<NQKV / 256, b256, 0, stream>>>(bq, bk, bv, bcat);
  f2b3_kernel<<<4096, b256, 0, stream>>>(wq, wk, wv, wbuf, nHH4);
  gemm256<EPI_QKV, false><<<gQKV3, b512, 0, stream>>>(xb, wbuf, qkv, bcat, nullptr,
                                                      S, NQKV, H_DIM, H_DIM);
  transpose_kernel<<<(S / 64) * (H_DIM / 64), b256, 0, stream>>>(qkv + 2 * H_DIM, vtb, S, NQKV);
  attn_kernel<<<gAttn, b256, 0, stream>>>(qkv, qkv + H_DIM, vtb, hat, S, NQKV);
  f2b_kernel<<<4096, b256, 0, stream>>>(wo, wbuf, nHH4);
  gemm256<EPI_PART, true><<<gO, b512, 0, stream>>>(hat, wbuf, pbuf, bo, nullptr,
                                                   S, H_DIM, H_DIM, H_DIM / 2);
  reduce_down<<<2048, b256, 0, stream>>>(pbuf, hidden, h1, n4HH, n4HH);

  // MLP block
  rmsnorm_kernel<<<S, b256, 0, stream>>>(h1, ln2, xb);
  f2b_kernel<<<4096, b256, 0, stream>>>(wg, wbuf, nFH4);
  gemm256<EPI_SILU, false><<<gFF, b512, 0, stream>>>(xb, wbuf, sg, nullptr, nullptr,
                                                     S, FF_DIM, H_DIM, H_DIM);
  f2b_kernel<<<4096, b256, 0, stream>>>(wu, wbuf, nFH4);
  gemm256<EPI_MUL, false><<<gFF, b512, 0, stream>>>(xb, wbuf, tb, nullptr, sg,
                                                    S, FF_DIM, H_DIM, H_DIM);
  f2b_kernel<<<4096, b256, 0, stream>>>(wd, wbuf, nFH4);
  gemm256<EPI_PART, true><<<gDW, b512, 0, stream>>>(tb, wbuf, pbuf, nullptr, nullptr,
                                                    S, H_DIM, FF_DIM, FF_DIM / 2);
  reduce_down<<<2048, b256, 0, stream>>>(pbuf, h1, out, n4HH, n4HH);
}

// Round 10
// 1520.467 us; speedup vs baseline: 1.2048x; 1.1042x over previous
//
#include <hip/hip_runtime.h>
#include <math.h>

#define H_DIM 4096
#define NHEAD 32
#define HD 128
#define FF_DIM 14336

typedef unsigned short u16;
typedef __attribute__((ext_vector_type(8))) short bf16x8;
typedef __attribute__((ext_vector_type(4))) float f32x4;
typedef __attribute__((ext_vector_type(4))) unsigned short u16x4;

typedef const __attribute__((address_space(1))) void* gas_ptr;
typedef __attribute__((address_space(3))) void* las_ptr;

__device__ __forceinline__ void gload_lds16(const void* g, void* l) {
  __builtin_amdgcn_global_load_lds((gas_ptr)g, (las_ptr)l, 16, 0, 0);
}

__device__ __forceinline__ u16 f32_to_bf16(float f) {
  unsigned int u = __float_as_uint(f);
  u = (u + 0x7FFFu + ((u >> 16) & 1u)) >> 16;
  return (u16)u;
}
__device__ __forceinline__ float bf16_to_f32(u16 x) {
  return __uint_as_float(((unsigned int)x) << 16);
}

// read-once fp32 -> bf16 (non-temporal load keeps weight fp32 out of L2;
// output uses regular store since the next GEMM reads it back soon)
__device__ __forceinline__ void conv4(const float* __restrict__ in,
                                      u16* __restrict__ out, long i) {
  const f32x4* p = reinterpret_cast<const f32x4*>(in) + i;
  f32x4 v = __builtin_nontemporal_load(p);
  u16x4 o;
  o.x = f32_to_bf16(v.x); o.y = f32_to_bf16(v.y);
  o.z = f32_to_bf16(v.z); o.w = f32_to_bf16(v.w);
  reinterpret_cast<u16x4*>(out)[i] = o;
}

// ---------------- fp32 -> bf16 weight conversion ----------------
__global__ void f2b_kernel(const float* __restrict__ in, u16* __restrict__ out, long n4) {
  long i = (long)blockIdx.x * blockDim.x + threadIdx.x;
  long stride = (long)gridDim.x * blockDim.x;
  for (; i < n4; i += stride) conv4(in, out, i);
}

// three equal-size weights -> one contiguous bf16 buffer
__global__ void f2b3_kernel(const float* __restrict__ a, const float* __restrict__ b,
                            const float* __restrict__ c, u16* __restrict__ out, long n4each) {
  long i = (long)blockIdx.x * blockDim.x + threadIdx.x;
  long st = (long)gridDim.x * blockDim.x;
  long tot = 3 * n4each;
  for (; i < tot; i += st) {
    const float* src; long j;
    if (i < n4each)            { src = a; j = i; }
    else if (i < 2 * n4each)   { src = b; j = i - n4each; }
    else                       { src = c; j = i - 2 * n4each; }
    const f32x4* p = reinterpret_cast<const f32x4*>(src) + j;
    f32x4 v = __builtin_nontemporal_load(p);
    u16x4 o;
    o.x = f32_to_bf16(v.x); o.y = f32_to_bf16(v.y);
    o.z = f32_to_bf16(v.z); o.w = f32_to_bf16(v.w);
    reinterpret_cast<u16x4*>(out)[i] = o;
  }
}

// ---------------- bias concat (fp32) ----------------
__global__ void bias_concat_kernel(const float* __restrict__ a, const float* __restrict__ b,
                                   const float* __restrict__ c, float* __restrict__ out) {
  int i = blockIdx.x * blockDim.x + threadIdx.x;
  float v;
  if (i < 4096) v = a[i];
  else if (i < 8192) v = b[i - 4096];
  else v = c[i - 8192];
  out[i] = v;
}

// ---------------- RMSNorm (fp32 in, bf16 out) ----------------
__global__ void rmsnorm_kernel(const float* __restrict__ in, const float* __restrict__ w,
                               u16* __restrict__ out) {
  int row = blockIdx.x;
  int tid = threadIdx.x;
  const float4* x4 = reinterpret_cast<const float4*>(in + (size_t)row * H_DIM);
  float4 vv[4];
  float ss = 0.f;
#pragma unroll
  for (int it = 0; it < 4; ++it) {
    float4 v = x4[tid + it * 256];
    vv[it] = v;
    ss += v.x * v.x + v.y * v.y + v.z * v.z + v.w * v.w;
  }
#pragma unroll
  for (int off = 1; off < 64; off <<= 1) ss += __shfl_xor(ss, off);
  __shared__ float part[4];
  if ((tid & 63) == 0) part[tid >> 6] = ss;
  __syncthreads();
  float tot = part[0] + part[1] + part[2] + part[3];
  float rinv = rsqrtf(tot * (1.0f / H_DIM) + 1e-6f);
  const float4* w4 = reinterpret_cast<const float4*>(w);
  u16* orow = out + (size_t)row * H_DIM;
#pragma unroll
  for (int it = 0; it < 4; ++it) {
    float4 v = vv[it];
    float4 wv = w4[tid + it * 256];
    ushort4 o;
    o.x = f32_to_bf16(v.x * rinv * wv.x);
    o.y = f32_to_bf16(v.y * rinv * wv.y);
    o.z = f32_to_bf16(v.z * rinv * wv.z);
    o.w = f32_to_bf16(v.w * rinv * wv.w);
    reinterpret_cast<ushort4*>(orow)[tid + it * 256] = o;
  }
}

// ================= 256x256 8-phase bf16 GEMM (T1+T2+T3+T4+T5) =================
// EXACT round-6 proven structure (best measured: 288us FF, MfmaUtil 35.5%,
// 0 bank conflicts, VGPR 112).
// Lessons ledger:
//  r5: unified VGPR budget 256/wave; reg-staged conversion pipelines spill.
//  r8: never co-schedule converter blocks with this kernel (L2 B-panel evict).
//  r9: frag-prefetch hoist is NEUTRAL — compiler's counted lgkmcnt already
//      overlaps ds-read drain with MFMA; extra regs only hurt. Keep as-is.
enum { EPI_QKV = 0, EPI_O = 1, EPI_SILU = 2, EPI_MUL = 3, EPI_PART = 4 };

template <int EPI, bool SPLIT>
__global__ __launch_bounds__(512, 2) void gemm256(
    const u16* __restrict__ A, const u16* __restrict__ B, void* __restrict__ outp,
    const float* __restrict__ bias, const void* __restrict__ extra,
    int M, int N, int K, int kLen) {
  __shared__ __align__(16) u16 As[2][256 * 64];
  __shared__ __align__(16) u16 Bs[2][256 * 64];
  const int tid = threadIdx.x;
  const int wid = tid >> 6, lane = tid & 63;
  const int lg = lane >> 4, li = lane & 15;
  const int wr = (wid >> 2) << 7;  // 0 / 128
  const int wc = (wid & 3) << 6;   // 0,64,128,192

  const int nbm = M >> 8, nbn = N >> 8;
  const int nb = nbm * nbn;
  int wg = (blockIdx.x & 7) * (gridDim.x >> 3) + (blockIdx.x >> 3);
  int s = 0;
  if (SPLIT) { s = wg / nb; wg -= s * nb; }
  const int m0 = (wg % nbm) << 8, n0 = (wg / nbm) << 8;
  const int kB = SPLIT ? s * kLen : 0;
  const int NT = kLen >> 6;

  // staging source pointers (pre-inverse-swizzled) + LDS dest offsets
  const int r8 = tid >> 3;
  const int sl = ((tid & 7) ^ (r8 & 7)) << 3;
  const u16* sA[2][2];
  const u16* sB[2][2];
  int ldo[2][2];
#pragma unroll
  for (int P = 0; P < 2; ++P)
#pragma unroll
    for (int h = 0; h < 2; ++h) {
      int lr = P * 128 + h * 64 + r8;
      int ra = (lr & 63) | ((lr >> 1) & 64) | ((lr << 1) & 128);
      int rb = (lr & 31) | ((lr & 96) << 1) | ((lr & 128) >> 2);
      sA[P][h] = A + (size_t)(m0 + ra) * K + kB + sl;
      sB[P][h] = B + (size_t)(n0 + rb) * K + kB + sl;
      ldo[P][h] = (P * 128 + h * 64 + (wid << 3)) << 6;
    }

  auto stageA = [&](int P, int d, int ko) {
#pragma unroll
    for (int h = 0; h < 2; ++h)
      gload_lds16(sA[P][h] + ko, (void*)(&As[d][ldo[P][h]]));
  };
  auto stageB = [&](int P, int d, int ko) {
#pragma unroll
    for (int h = 0; h < 2; ++h)
      gload_lds16(sB[P][h] + ko, (void*)(&Bs[d][ldo[P][h]]));
  };

  bf16x8 a[4][2], b[4][2];
  f32x4 acc[8][4] = {};
  const int s20 = (lg ^ (li & 7)) << 3;
  const int s21 = ((4 + lg) ^ (li & 7)) << 3;

  auto ldA = [&](int d, int set) {
#pragma unroll
    for (int i = 0; i < 4; ++i) {
      int g = wr + set * 64 + i * 16;
      int lb = (g & 63) | ((g >> 1) & 64) | ((g << 1) & 128);
      const u16* base = &As[d][(lb + li) << 6];
      a[i][0] = *reinterpret_cast<const bf16x8*>(base + s20);
      a[i][1] = *reinterpret_cast<const bf16x8*>(base + s21);
    }
  };
  auto ldB = [&](int d, int set) {
#pragma unroll
    for (int jj = 0; jj < 2; ++jj) {
      int hh = wc + (set * 2 + jj) * 16;
      int lb = ((hh & 32) << 2) | ((hh & 192) >> 1) | (hh & 31);
      const u16* base = &Bs[d][(lb + li) << 6];
      b[set * 2 + jj][0] = *reinterpret_cast<const bf16x8*>(base + s20);
      b[set * 2 + jj][1] = *reinterpret_cast<const bf16x8*>(base + s21);
    }
  };
  auto mm = [&](int iset, int jset) {
    __builtin_amdgcn_s_setprio(1);
#pragma unroll
    for (int i = 0; i < 4; ++i)
#pragma unroll
      for (int jj = 0; jj < 2; ++jj)
#pragma unroll
        for (int kk = 0; kk < 2; ++kk)
          acc[iset * 4 + i][jset * 2 + jj] = __builtin_amdgcn_mfma_f32_16x16x32_bf16(
              a[i][kk], b[jset * 2 + jj][kk], acc[iset * 4 + i][jset * 2 + jj], 0, 0, 0);
    __builtin_amdgcn_s_setprio(0);
  };

  // prologue: stage tiles 0 and 1
  stageA(0, 0, 0); stageB(0, 0, 0); stageB(1, 0, 0); stageA(1, 0, 0);
  if (NT > 1) {
    stageA(0, 1, 64); stageB(0, 1, 64); stageB(1, 1, 64); stageA(1, 1, 64);
    asm volatile("s_waitcnt vmcnt(8)" ::: "memory");
  } else {
    asm volatile("s_waitcnt vmcnt(0)" ::: "memory");
  }
  __builtin_amdgcn_s_barrier();

  for (int t = 0; t < NT; ++t) {
    int d = t & 1;
    bool pf = (t + 2) < NT;
    int ko = (t + 2) << 6;
    // ---- phase 1: reads A1+B1; MFMA quadrant (i0-3, j0-1)
    ldB(d, 0); ldA(d, 0);
    __builtin_amdgcn_s_barrier();
    mm(0, 0);
    __builtin_amdgcn_s_barrier();
    // ---- phase 2: reads B2; stage t+2.{A1,B1}; MFMA (i0-3, j2-3)
    ldB(d, 1);
    if (pf) { stageA(0, d, ko); stageB(0, d, ko); }
    __builtin_amdgcn_s_barrier();
    mm(0, 1);
    __builtin_amdgcn_s_barrier();
    // ---- phase 3: reads A2; stage t+2.B2; MFMA (i4-7, j0-1)
    ldA(d, 1);
    if (pf) stageB(1, d, ko);
    __builtin_amdgcn_s_barrier();
    mm(1, 0);
    __builtin_amdgcn_s_barrier();
    // ---- phase 4: stage t+2.A2; counted vmcnt; MFMA (i4-7, j2-3)
    if (pf) {
      stageA(1, d, ko);
      asm volatile("s_waitcnt vmcnt(6)" ::: "memory");
    } else {
      asm volatile("s_waitcnt vmcnt(0)" ::: "memory");
    }
    __builtin_amdgcn_s_barrier();
    mm(1, 1);
    __builtin_amdgcn_s_barrier();
  }

  // ---- epilogue
#pragma unroll
  for (int i = 0; i < 8; ++i) {
#pragma unroll
    for (int j = 0; j < 4; ++j) {
      int col = n0 + wc + j * 16 + li;
      float bv = 0.f;
      if (EPI == EPI_QKV || EPI == EPI_O) bv = bias[col];
      if (EPI == EPI_PART && bias != nullptr && s == 0) bv = bias[col];
#pragma unroll
      for (int r = 0; r < 4; ++r) {
        int row = m0 + wr + i * 16 + lg * 4 + r;
        float v = acc[i][j][r] + bv;
        size_t idx = (size_t)row * N + col;
        if (EPI == EPI_QKV) {
          ((u16*)outp)[idx] = f32_to_bf16(v);
        } else if (EPI == EPI_O) {
          const float* res = (const float*)extra;
          ((float*)outp)[idx] = res[idx] + v;
        } else if (EPI == EPI_SILU) {
          float sv = v / (1.f + __expf(-v));
          ((u16*)outp)[idx] = f32_to_bf16(sv);
        } else if (EPI == EPI_MUL) {
          const u16* sg = (const u16*)extra;
          ((u16*)outp)[idx] = f32_to_bf16(v * bf16_to_f32(sg[idx]));
        } else {  // EPI_PART: split-K partial, plain fp32 (bias folded at s==0)
          ((float*)outp)[(size_t)s * M * N + idx] = v;
        }
      }
    }
  }
}

// ---------------- split-K reduce + residual: out = res + p0 + p1 ----------------
// Partials are read exactly once -> non-temporal loads; final out is never
// re-read on device -> non-temporal store.
__global__ void reduce_down(const float* __restrict__ p, const float* __restrict__ res,
                            float* __restrict__ out, long n4, long str4) {
  long i = (long)blockIdx.x * blockDim.x + threadIdx.x;
  long st = (long)gridDim.x * blockDim.x;
  for (; i < n4; i += st) {
    f32x4 h = reinterpret_cast<const f32x4*>(res)[i];
    f32x4 p0 = __builtin_nontemporal_load(reinterpret_cast<const f32x4*>(p) + i);
    f32x4 p1 = __builtin_nontemporal_load(reinterpret_cast<const f32x4*>(p) + i + str4);
    f32x4 o;
    o.x = h.x + p0.x + p1.x; o.y = h.y + p0.y + p1.y;
    o.z = h.z + p0.z + p1.z; o.w = h.w + p0.w + p1.w;
    __builtin_nontemporal_store(o, reinterpret_cast<f32x4*>(out) + i);
  }
}

// ---------------- bf16 transpose: in[S][ldin] (64-col slice) -> out[.][S] ----------------
__global__ void transpose_kernel(const u16* __restrict__ in, u16* __restrict__ out,
                                 int S, int ldin) {
  __shared__ __align__(16) u16 t[64][80];
  int sbT = S >> 6;
  int bs = blockIdx.x % sbT, bc = blockIdx.x / sbT;
  int s0 = bs << 6, c0 = bc << 6;
  int tid = threadIdx.x;
  int ir = tid >> 3;
  int jc = (tid & 7) * 8;
#pragma unroll
  for (int h = 0; h < 2; ++h) {
    int sr = ir + h * 32;
    uint4 v = *reinterpret_cast<const uint4*>(in + (size_t)(s0 + sr) * ldin + c0 + jc);
    *reinterpret_cast<uint4*>(&t[sr][jc]) = v;
  }
  __syncthreads();
  int d = tid >> 3;
  int ss = (tid & 7) * 8;
#pragma unroll
  for (int h = 0; h < 2; ++h) {
    int dd = d + h * 32;
    u16 tmp[8];
#pragma unroll
    for (int e = 0; e < 8; ++e) tmp[e] = t[ss + e][dd];
    *reinterpret_cast<uint4*>(out + (size_t)(c0 + dd) * S + s0 + ss) =
        *reinterpret_cast<const uint4*>(tmp);
  }
}

// ---------------- causal flash attention (CLEAN — no extra branches) --------
// QBLK=32, KVBLK=64, balanced tile pairs, XOR-swizzled P-LDS. VGPR-limited
// occupancy: keep this kernel single-purpose (round-7 lesson: a co-compiled
// conv branch inflated VGPR 84->172 and tripled runtime).
__global__ __launch_bounds__(256) void attn_kernel(
    const u16* __restrict__ q, const u16* __restrict__ k,
    const u16* __restrict__ vt, u16* __restrict__ o, int S, int ldqk) {
  __shared__ __align__(16) u16 plds[4][32 * 64];
  int tid = threadIdx.x, wid = tid >> 6, lane = tid & 63;
  int lg = lane >> 4, li = lane & 15;
  int nwg = gridDim.x;
  int sbid = (blockIdx.x & 7) * (nwg >> 3) + (blockIdx.x >> 3);
  int task = sbid * 4 + wid;
  int pairs = S >> 6;
  int head = task / pairs;
  int pi = task - head * pairs;
  const float scale = 0.08838834764831845f;
  u16* pl = plds[wid];

  for (int tix = 0; tix < 2; ++tix) {
    int qt = tix ? ((S >> 5) - 1 - pi) : pi;
    int q0 = qt << 5;

    bf16x8 aq[2][4];
#pragma unroll
    for (int fi = 0; fi < 2; ++fi) {
      const u16* qrow = q + (size_t)(q0 + fi * 16 + li) * ldqk + head * HD + lg * 8;
#pragma unroll
      for (int ks = 0; ks < 4; ++ks)
        aq[fi][ks] = *reinterpret_cast<const bf16x8*>(qrow + ks * 32);
    }

    f32x4 oacc[2][8] = {};
    float m_run[2][4], l_run[2][4];
#pragma unroll
    for (int fi = 0; fi < 2; ++fi)
#pragma unroll
      for (int r = 0; r < 4; ++r) { m_run[fi][r] = -INFINITY; l_run[fi][r] = 0.f; }

    int nkb = ((q0 + 31) >> 6) + 1;
    for (int kb = 0; kb < nkb; ++kb) {
      int kvbase = kb << 6;
      f32x4 sacc[2][4] = {};
#pragma unroll
      for (int cf = 0; cf < 4; ++cf) {
        const u16* krow = k + (size_t)(kvbase + cf * 16 + li) * ldqk + head * HD + lg * 8;
#pragma unroll
        for (int ks = 0; ks < 4; ++ks) {
          bf16x8 bk = *reinterpret_cast<const bf16x8*>(krow + ks * 32);
          sacc[0][cf] = __builtin_amdgcn_mfma_f32_16x16x32_bf16(aq[0][ks], bk, sacc[0][cf], 0, 0, 0);
          sacc[1][cf] = __builtin_amdgcn_mfma_f32_16x16x32_bf16(aq[1][ks], bk, sacc[1][cf], 0, 0, 0);
        }
      }
      bool bnd = (kvbase + 63) > q0;
      float alpha[2][4];
#pragma unroll
      for (int fi = 0; fi < 2; ++fi) {
#pragma unroll
        for (int r = 0; r < 4; ++r) {
          int row = q0 + fi * 16 + lg * 4 + r;
#pragma unroll
          for (int cf = 0; cf < 4; ++cf) {
            float sv = sacc[fi][cf][r] * scale;
            if (bnd && (kvbase + cf * 16 + li) > row) sv = -INFINITY;
            sacc[fi][cf][r] = sv;
          }
          float mv = fmaxf(fmaxf(sacc[fi][0][r], sacc[fi][1][r]),
                           fmaxf(sacc[fi][2][r], sacc[fi][3][r]));
#pragma unroll
          for (int off = 1; off < 16; off <<= 1) mv = fmaxf(mv, __shfl_xor(mv, off));
          float mnew = fmaxf(m_run[fi][r], mv);
          alpha[fi][r] = __expf(m_run[fi][r] - mnew);
          m_run[fi][r] = mnew;
          float ps = 0.f;
#pragma unroll
          for (int cf = 0; cf < 4; ++cf) {
            float pv = __expf(sacc[fi][cf][r] - mnew);
            sacc[fi][cf][r] = pv;
            ps += pv;
          }
#pragma unroll
          for (int off = 1; off < 16; off <<= 1) ps += __shfl_xor(ps, off);
          l_run[fi][r] = l_run[fi][r] * alpha[fi][r] + ps;
        }
      }
#pragma unroll
      for (int fi = 0; fi < 2; ++fi)
#pragma unroll
        for (int df = 0; df < 8; ++df)
#pragma unroll
          for (int r = 0; r < 4; ++r) oacc[fi][df][r] *= alpha[fi][r];
#pragma unroll
      for (int fi = 0; fi < 2; ++fi)
#pragma unroll
        for (int cf = 0; cf < 4; ++cf)
#pragma unroll
          for (int r = 0; r < 4; ++r) {
            int row = fi * 16 + lg * 4 + r;
            int el = row * 64 + cf * 16 + li;
            pl[el ^ ((row & 7) << 3)] = f32_to_bf16(sacc[fi][cf][r]);
          }
      asm volatile("s_waitcnt lgkmcnt(0)" ::: "memory");
      __builtin_amdgcn_sched_barrier(0);
#pragma unroll
      for (int kk = 0; kk < 2; ++kk) {
        bf16x8 pa[2];
#pragma unroll
        for (int fi = 0; fi < 2; ++fi) {
          int row = fi * 16 + li;
          int el = row * 64 + kk * 32 + lg * 8;
          pa[fi] = *reinterpret_cast<const bf16x8*>(pl + (el ^ ((row & 7) << 3)));
        }
        const u16* vb = vt + kvbase + kk * 32 + lg * 8;
#pragma unroll
        for (int df = 0; df < 8; ++df) {
          bf16x8 bv = *reinterpret_cast<const bf16x8*>(vb + (size_t)(head * HD + df * 16 + li) * S);
          oacc[0][df] = __builtin_amdgcn_mfma_f32_16x16x32_bf16(pa[0], bv, oacc[0][df], 0, 0, 0);
          oacc[1][df] = __builtin_amdgcn_mfma_f32_16x16x32_bf16(pa[1], bv, oacc[1][df], 0, 0, 0);
        }
      }
    }
#pragma unroll
    for (int fi = 0; fi < 2; ++fi)
#pragma unroll
      for (int r = 0; r < 4; ++r) {
        float inv = 1.0f / l_run[fi][r];
        int row = q0 + fi * 16 + lg * 4 + r;
        u16* orow = o + (size_t)row * H_DIM + head * HD;
#pragma unroll
        for (int df = 0; df < 8; ++df)
          orow[df * 16 + li] = f32_to_bf16(oacc[fi][df][r] * inv);
      }
  }
}

extern "C" void kernel_launch(void* const* d_in, const int* in_sizes, int n_in,
                              void* d_out, int out_size, void* d_ws, size_t ws_size,
                              hipStream_t stream) {
  (void)n_in; (void)out_size;
  const float* hidden = (const float*)d_in[0];
  const float* wq = (const float*)d_in[2];
  const float* bq = (const float*)d_in[3];
  const float* wk = (const float*)d_in[4];
  const float* bk = (const float*)d_in[5];
  const float* wv = (const float*)d_in[6];
  const float* bv = (const float*)d_in[7];
  const float* wo = (const float*)d_in[8];
  const float* bo = (const float*)d_in[9];
  const float* wg = (const float*)d_in[10];
  const float* wu = (const float*)d_in[11];
  const float* wd = (const float*)d_in[12];
  const float* ln1 = (const float*)d_in[13];
  const float* ln2 = (const float*)d_in[14];
  float* out = (float*)d_out;

  int S = in_sizes[0] / H_DIM;  // 2048
  int NQKV = 3 * H_DIM;         // 12288

  char* ws = (char*)d_ws;
  size_t off = 0;
  auto alloc = [&](size_t bytes) {
    void* p = ws + off;
    off += (bytes + 255) & ~(size_t)255;
    return p;
  };
  u16* wbuf = (u16*)alloc((size_t)FF_DIM * H_DIM * 2);  // shared weight bf16 buffer
  u16* xb   = (u16*)alloc((size_t)S * H_DIM * 2);
  u16* qkv  = (u16*)alloc((size_t)S * NQKV * 2);        // [S][12288]
  u16* vtb  = (u16*)alloc((size_t)S * H_DIM * 2);       // V^T [4096][S]
  u16* hat  = (u16*)alloc((size_t)S * H_DIM * 2);
  float* h1 = (float*)alloc((size_t)S * H_DIM * 4);
  u16* sg   = (u16*)alloc((size_t)S * FF_DIM * 2);
  u16* tb   = (u16*)alloc((size_t)S * FF_DIM * 2);
  float* bcat = (float*)alloc((size_t)NQKV * 4);
  if (off > ws_size) return;
  // split-K partials overlay qkv+vtb (both dead by O-proj / down-proj time):
  // need 2*S*H*4 = 67.11 MB; qkv(50.33) + vtb(16.78) = 67.11 MB exactly.
  float* pbuf = (float*)qkv;

  dim3 b256(256), b512(512);
  long nHH4 = (long)H_DIM * H_DIM / 4;
  long nFH4 = (long)FF_DIM * H_DIM / 4;
  int gQKV3 = (S / 256) * (NQKV / 256);      // 384
  int gO    = 2 * (S / 256) * (H_DIM / 256); // 256 (split-K=2)
  int gFF   = (S / 256) * (FF_DIM / 256);    // 448
  int gDW   = 2 * (S / 256) * (H_DIM / 256); // 256 (split-K=2)
  long n4HH = (long)S * H_DIM / 4;
  int gAttn = (NHEAD * (S / 64)) / 4;        // 256

  // attention block
  rmsnorm_kernel<<<S, b256, 0, stream>>>(hidden, ln1, xb);
  bias_concat_kernel<<<NQKV / 256, b256, 0, stream>>>(bq, bk, bv, bcat);
  f2b3_kernel<<<4096, b256, 0, stream>>>(wq, wk, wv, wbuf, nHH4);
  gemm256<EPI_QKV, false><<<gQKV3, b512, 0, stream>>>(xb, wbuf, qkv, bcat, nullptr,
                                                      S, NQKV, H_DIM, H_DIM);
  transpose_kernel<<<(S / 64) * (H_DIM / 64), b256, 0, stream>>>(qkv + 2 * H_DIM, vtb, S, NQKV);
  attn_kernel<<<gAttn, b256, 0, stream>>>(qkv, qkv + H_DIM, vtb, hat, S, NQKV);
  f2b_kernel<<<4096, b256, 0, stream>>>(wo, wbuf, nHH4);
  gemm256<EPI_PART, true><<<gO, b512, 0, stream>>>(hat, wbuf, pbuf, bo, nullptr,
                                                   S, H_DIM, H_DIM, H_DIM / 2);
  reduce_down<<<2048, b256, 0, stream>>>(pbuf, hidden, h1, n4HH, n4HH);

  // MLP block
  rmsnorm_kernel<<<S, b256, 0, stream>>>(h1, ln2, xb);
  f2b_kernel<<<4096, b256, 0, stream>>>(wg, wbuf, nFH4);
  gemm256<EPI_SILU, false><<<gFF, b512, 0, stream>>>(xb, wbuf, sg, nullptr, nullptr,
                                                     S, FF_DIM, H_DIM, H_DIM);
  f2b_kernel<<<4096, b256, 0, stream>>>(wu, wbuf, nFH4);
  gemm256<EPI_MUL, false><<<gFF, b512, 0, stream>>>(xb, wbuf, tb, nullptr, sg,
                                                    S, FF_DIM, H_DIM, H_DIM);
  f2b_kernel<<<4096, b256, 0, stream>>>(wd, wbuf, nFH4);
  gemm256<EPI_PART, true><<<gDW, b512, 0, stream>>>(tb, wbuf, pbuf, nullptr, nullptr,
                                                    S, H_DIM, FF_DIM, FF_DIM / 2);
  reduce_down<<<2048, b256, 0, stream>>>(pbuf, h1, out, n4HH, n4HH);
}

// Round 11
// 1481.133 us; speedup vs baseline: 1.2368x; 1.0266x over previous
//
#include <hip/hip_runtime.h>
#include <math.h>

#define H_DIM 4096
#define NHEAD 32
#define HD 128
#define FF_DIM 14336

typedef unsigned short u16;
typedef __attribute__((ext_vector_type(8))) short bf16x8;
typedef __attribute__((ext_vector_type(4))) float f32x4;
typedef __attribute__((ext_vector_type(4))) unsigned short u16x4;

typedef const __attribute__((address_space(1))) void* gas_ptr;
typedef __attribute__((address_space(3))) void* las_ptr;

__device__ __forceinline__ void gload_lds16(const void* g, void* l) {
  __builtin_amdgcn_global_load_lds((gas_ptr)g, (las_ptr)l, 16, 0, 0);
}

__device__ __forceinline__ u16 f32_to_bf16(float f) {
  unsigned int u = __float_as_uint(f);
  u = (u + 0x7FFFu + ((u >> 16) & 1u)) >> 16;
  return (u16)u;
}
__device__ __forceinline__ float bf16_to_f32(u16 x) {
  return __uint_as_float(((unsigned int)x) << 16);
}

// read-once fp32 -> bf16 (non-temporal load keeps weight fp32 out of L2 so the
// following GEMM's bf16 panels stay resident — r10: -137us total)
__device__ __forceinline__ void conv4(const float* __restrict__ in,
                                      u16* __restrict__ out, long i) {
  const f32x4* p = reinterpret_cast<const f32x4*>(in) + i;
  f32x4 v = __builtin_nontemporal_load(p);
  u16x4 o;
  o.x = f32_to_bf16(v.x); o.y = f32_to_bf16(v.y);
  o.z = f32_to_bf16(v.z); o.w = f32_to_bf16(v.w);
  reinterpret_cast<u16x4*>(out)[i] = o;
}

// ---------------- fp32 -> bf16 weight conversion ----------------
__global__ void f2b_kernel(const float* __restrict__ in, u16* __restrict__ out, long n4) {
  long i = (long)blockIdx.x * blockDim.x + threadIdx.x;
  long stride = (long)gridDim.x * blockDim.x;
  for (; i < n4; i += stride) conv4(in, out, i);
}

// three equal-size weights -> one contiguous bf16 buffer
__global__ void f2b3_kernel(const float* __restrict__ a, const float* __restrict__ b,
                            const float* __restrict__ c, u16* __restrict__ out, long n4each) {
  long i = (long)blockIdx.x * blockDim.x + threadIdx.x;
  long st = (long)gridDim.x * blockDim.x;
  long tot = 3 * n4each;
  for (; i < tot; i += st) {
    const float* src; long j;
    if (i < n4each)            { src = a; j = i; }
    else if (i < 2 * n4each)   { src = b; j = i - n4each; }
    else                       { src = c; j = i - 2 * n4each; }
    const f32x4* p = reinterpret_cast<const f32x4*>(src) + j;
    f32x4 v = __builtin_nontemporal_load(p);
    u16x4 o;
    o.x = f32_to_bf16(v.x); o.y = f32_to_bf16(v.y);
    o.z = f32_to_bf16(v.z); o.w = f32_to_bf16(v.w);
    reinterpret_cast<u16x4*>(out)[i] = o;
  }
}

// ---------------- bias concat (fp32) ----------------
__global__ void bias_concat_kernel(const float* __restrict__ a, const float* __restrict__ b,
                                   const float* __restrict__ c, float* __restrict__ out) {
  int i = blockIdx.x * blockDim.x + threadIdx.x;
  float v;
  if (i < 4096) v = a[i];
  else if (i < 8192) v = b[i - 4096];
  else v = c[i - 8192];
  out[i] = v;
}

// ---------------- RMSNorm (fp32 in, bf16 out) ----------------
__global__ void rmsnorm_kernel(const float* __restrict__ in, const float* __restrict__ w,
                               u16* __restrict__ out) {
  int row = blockIdx.x;
  int tid = threadIdx.x;
  const float4* x4 = reinterpret_cast<const float4*>(in + (size_t)row * H_DIM);
  float4 vv[4];
  float ss = 0.f;
#pragma unroll
  for (int it = 0; it < 4; ++it) {
    float4 v = x4[tid + it * 256];
    vv[it] = v;
    ss += v.x * v.x + v.y * v.y + v.z * v.z + v.w * v.w;
  }
#pragma unroll
  for (int off = 1; off < 64; off <<= 1) ss += __shfl_xor(ss, off);
  __shared__ float part[4];
  if ((tid & 63) == 0) part[tid >> 6] = ss;
  __syncthreads();
  float tot = part[0] + part[1] + part[2] + part[3];
  float rinv = rsqrtf(tot * (1.0f / H_DIM) + 1e-6f);
  const float4* w4 = reinterpret_cast<const float4*>(w);
  u16* orow = out + (size_t)row * H_DIM;
#pragma unroll
  for (int it = 0; it < 4; ++it) {
    float4 v = vv[it];
    float4 wv = w4[tid + it * 256];
    ushort4 o;
    o.x = f32_to_bf16(v.x * rinv * wv.x);
    o.y = f32_to_bf16(v.y * rinv * wv.y);
    o.z = f32_to_bf16(v.z * rinv * wv.z);
    o.w = f32_to_bf16(v.w * rinv * wv.w);
    reinterpret_cast<ushort4*>(orow)[tid + it * 256] = o;
  }
}

// ================= 256x256 8-phase bf16 GEMM (T1+T2+T3+T4+T5) =================
// EXACT round-6 proven structure (best measured: 288us FF, MfmaUtil 35.5%,
// 0 bank conflicts, VGPR 112).
// Lessons ledger:
//  r5: unified VGPR budget 256/wave; reg-staged conversion pipelines spill.
//  r8: never co-schedule converter blocks with this kernel (L2 B-panel evict).
//  r9: frag-prefetch hoist is NEUTRAL — compiler's counted lgkmcnt already
//      overlaps ds-read drain with MFMA; extra regs only hurt. Keep as-is.
enum { EPI_QKV = 0, EPI_O = 1, EPI_SILU = 2, EPI_MUL = 3, EPI_PART = 4 };

template <int EPI, bool SPLIT>
__global__ __launch_bounds__(512, 2) void gemm256(
    const u16* __restrict__ A, const u16* __restrict__ B, void* __restrict__ outp,
    const float* __restrict__ bias, const void* __restrict__ extra,
    int M, int N, int K, int kLen) {
  __shared__ __align__(16) u16 As[2][256 * 64];
  __shared__ __align__(16) u16 Bs[2][256 * 64];
  const int tid = threadIdx.x;
  const int wid = tid >> 6, lane = tid & 63;
  const int lg = lane >> 4, li = lane & 15;
  const int wr = (wid >> 2) << 7;  // 0 / 128
  const int wc = (wid & 3) << 6;   // 0,64,128,192

  const int nbm = M >> 8, nbn = N >> 8;
  const int nb = nbm * nbn;
  int wg = (blockIdx.x & 7) * (gridDim.x >> 3) + (blockIdx.x >> 3);
  int s = 0;
  if (SPLIT) { s = wg / nb; wg -= s * nb; }
  const int m0 = (wg % nbm) << 8, n0 = (wg / nbm) << 8;
  const int kB = SPLIT ? s * kLen : 0;
  const int NT = kLen >> 6;

  // staging source pointers (pre-inverse-swizzled) + LDS dest offsets
  const int r8 = tid >> 3;
  const int sl = ((tid & 7) ^ (r8 & 7)) << 3;
  const u16* sA[2][2];
  const u16* sB[2][2];
  int ldo[2][2];
#pragma unroll
  for (int P = 0; P < 2; ++P)
#pragma unroll
    for (int h = 0; h < 2; ++h) {
      int lr = P * 128 + h * 64 + r8;
      int ra = (lr & 63) | ((lr >> 1) & 64) | ((lr << 1) & 128);
      int rb = (lr & 31) | ((lr & 96) << 1) | ((lr & 128) >> 2);
      sA[P][h] = A + (size_t)(m0 + ra) * K + kB + sl;
      sB[P][h] = B + (size_t)(n0 + rb) * K + kB + sl;
      ldo[P][h] = (P * 128 + h * 64 + (wid << 3)) << 6;
    }

  auto stageA = [&](int P, int d, int ko) {
#pragma unroll
    for (int h = 0; h < 2; ++h)
      gload_lds16(sA[P][h] + ko, (void*)(&As[d][ldo[P][h]]));
  };
  auto stageB = [&](int P, int d, int ko) {
#pragma unroll
    for (int h = 0; h < 2; ++h)
      gload_lds16(sB[P][h] + ko, (void*)(&Bs[d][ldo[P][h]]));
  };

  bf16x8 a[4][2], b[4][2];
  f32x4 acc[8][4] = {};
  const int s20 = (lg ^ (li & 7)) << 3;
  const int s21 = ((4 + lg) ^ (li & 7)) << 3;

  auto ldA = [&](int d, int set) {
#pragma unroll
    for (int i = 0; i < 4; ++i) {
      int g = wr + set * 64 + i * 16;
      int lb = (g & 63) | ((g >> 1) & 64) | ((g << 1) & 128);
      const u16* base = &As[d][(lb + li) << 6];
      a[i][0] = *reinterpret_cast<const bf16x8*>(base + s20);
      a[i][1] = *reinterpret_cast<const bf16x8*>(base + s21);
    }
  };
  auto ldB = [&](int d, int set) {
#pragma unroll
    for (int jj = 0; jj < 2; ++jj) {
      int hh = wc + (set * 2 + jj) * 16;
      int lb = ((hh & 32) << 2) | ((hh & 192) >> 1) | (hh & 31);
      const u16* base = &Bs[d][(lb + li) << 6];
      b[set * 2 + jj][0] = *reinterpret_cast<const bf16x8*>(base + s20);
      b[set * 2 + jj][1] = *reinterpret_cast<const bf16x8*>(base + s21);
    }
  };
  auto mm = [&](int iset, int jset) {
    __builtin_amdgcn_s_setprio(1);
#pragma unroll
    for (int i = 0; i < 4; ++i)
#pragma unroll
      for (int jj = 0; jj < 2; ++jj)
#pragma unroll
        for (int kk = 0; kk < 2; ++kk)
          acc[iset * 4 + i][jset * 2 + jj] = __builtin_amdgcn_mfma_f32_16x16x32_bf16(
              a[i][kk], b[jset * 2 + jj][kk], acc[iset * 4 + i][jset * 2 + jj], 0, 0, 0);
    __builtin_amdgcn_s_setprio(0);
  };

  // prologue: stage tiles 0 and 1
  stageA(0, 0, 0); stageB(0, 0, 0); stageB(1, 0, 0); stageA(1, 0, 0);
  if (NT > 1) {
    stageA(0, 1, 64); stageB(0, 1, 64); stageB(1, 1, 64); stageA(1, 1, 64);
    asm volatile("s_waitcnt vmcnt(8)" ::: "memory");
  } else {
    asm volatile("s_waitcnt vmcnt(0)" ::: "memory");
  }
  __builtin_amdgcn_s_barrier();

  for (int t = 0; t < NT; ++t) {
    int d = t & 1;
    bool pf = (t + 2) < NT;
    int ko = (t + 2) << 6;
    // ---- phase 1: reads A1+B1; MFMA quadrant (i0-3, j0-1)
    ldB(d, 0); ldA(d, 0);
    __builtin_amdgcn_s_barrier();
    mm(0, 0);
    __builtin_amdgcn_s_barrier();
    // ---- phase 2: reads B2; stage t+2.{A1,B1}; MFMA (i0-3, j2-3)
    ldB(d, 1);
    if (pf) { stageA(0, d, ko); stageB(0, d, ko); }
    __builtin_amdgcn_s_barrier();
    mm(0, 1);
    __builtin_amdgcn_s_barrier();
    // ---- phase 3: reads A2; stage t+2.B2; MFMA (i4-7, j0-1)
    ldA(d, 1);
    if (pf) stageB(1, d, ko);
    __builtin_amdgcn_s_barrier();
    mm(1, 0);
    __builtin_amdgcn_s_barrier();
    // ---- phase 4: stage t+2.A2; counted vmcnt; MFMA (i4-7, j2-3)
    if (pf) {
      stageA(1, d, ko);
      asm volatile("s_waitcnt vmcnt(6)" ::: "memory");
    } else {
      asm volatile("s_waitcnt vmcnt(0)" ::: "memory");
    }
    __builtin_amdgcn_s_barrier();
    mm(1, 1);
    __builtin_amdgcn_s_barrier();
  }

  // ---- epilogue
#pragma unroll
  for (int i = 0; i < 8; ++i) {
#pragma unroll
    for (int j = 0; j < 4; ++j) {
      int col = n0 + wc + j * 16 + li;
      float bv = 0.f;
      if (EPI == EPI_QKV || EPI == EPI_O) bv = bias[col];
      if (EPI == EPI_PART && bias != nullptr && s == 0) bv = bias[col];
#pragma unroll
      for (int r = 0; r < 4; ++r) {
        int row = m0 + wr + i * 16 + lg * 4 + r;
        float v = acc[i][j][r] + bv;
        size_t idx = (size_t)row * N + col;
        if (EPI == EPI_QKV) {
          ((u16*)outp)[idx] = f32_to_bf16(v);
        } else if (EPI == EPI_O) {
          const float* res = (const float*)extra;
          ((float*)outp)[idx] = res[idx] + v;
        } else if (EPI == EPI_SILU) {
          float sv = v / (1.f + __expf(-v));
          ((u16*)outp)[idx] = f32_to_bf16(sv);
        } else if (EPI == EPI_MUL) {
          const u16* sg = (const u16*)extra;
          ((u16*)outp)[idx] = f32_to_bf16(v * bf16_to_f32(sg[idx]));
        } else {  // EPI_PART: split-K partial, plain fp32 (bias folded at s==0)
          ((float*)outp)[(size_t)s * M * N + idx] = v;
        }
      }
    }
  }
}

// ---------------- split-K reduce + residual: out = res + p0 + p1 ----------------
__global__ void reduce_down(const float* __restrict__ p, const float* __restrict__ res,
                            float* __restrict__ out, long n4, long str4) {
  long i = (long)blockIdx.x * blockDim.x + threadIdx.x;
  long st = (long)gridDim.x * blockDim.x;
  for (; i < n4; i += st) {
    f32x4 h = reinterpret_cast<const f32x4*>(res)[i];
    f32x4 p0 = __builtin_nontemporal_load(reinterpret_cast<const f32x4*>(p) + i);
    f32x4 p1 = __builtin_nontemporal_load(reinterpret_cast<const f32x4*>(p) + i + str4);
    f32x4 o;
    o.x = h.x + p0.x + p1.x; o.y = h.y + p0.y + p1.y;
    o.z = h.z + p0.z + p1.z; o.w = h.w + p0.w + p1.w;
    __builtin_nontemporal_store(o, reinterpret_cast<f32x4*>(out) + i);
  }
}

// ---------------- bf16 transpose: in[S][ldin] (64-col slice) -> out[.][S] ----------------
__global__ void transpose_kernel(const u16* __restrict__ in, u16* __restrict__ out,
                                 int S, int ldin) {
  __shared__ __align__(16) u16 t[64][80];
  int sbT = S >> 6;
  int bs = blockIdx.x % sbT, bc = blockIdx.x / sbT;
  int s0 = bs << 6, c0 = bc << 6;
  int tid = threadIdx.x;
  int ir = tid >> 3;
  int jc = (tid & 7) * 8;
#pragma unroll
  for (int h = 0; h < 2; ++h) {
    int sr = ir + h * 32;
    uint4 v = *reinterpret_cast<const uint4*>(in + (size_t)(s0 + sr) * ldin + c0 + jc);
    *reinterpret_cast<uint4*>(&t[sr][jc]) = v;
  }
  __syncthreads();
  int d = tid >> 3;
  int ss = (tid & 7) * 8;
#pragma unroll
  for (int h = 0; h < 2; ++h) {
    int dd = d + h * 32;
    u16 tmp[8];
#pragma unroll
    for (int e = 0; e < 8; ++e) tmp[e] = t[ss + e][dd];
    *reinterpret_cast<uint4*>(out + (size_t)(c0 + dd) * S + s0 + ss) =
        *reinterpret_cast<const uint4*>(tmp);
  }
}

// ---------------- causal flash attention (QBLK=16, 2 blocks/CU) -------------
// r10 diagnosis: old QBLK=32 pairing gave grid 256 = 1 block/CU = 1 wave/SIMD
// (occupancy 10.5%, latency-bound, MfmaUtil 5%). QBLK=16 halves the wave task
// -> 2048 tasks -> grid 512 = 2 blocks/CU, and drops VGPR (oacc/aq/sacc all
// halve) -> 2x wave-level latency hiding. Balanced pairs (pi, 127-pi) keep
// per-wave work constant (33 K-blocks). Keep kernel single-purpose (r7).
__global__ __launch_bounds__(256) void attn_kernel(
    const u16* __restrict__ q, const u16* __restrict__ k,
    const u16* __restrict__ vt, u16* __restrict__ o, int S, int ldqk) {
  __shared__ __align__(16) u16 plds[4][16 * 64];
  int tid = threadIdx.x, wid = tid >> 6, lane = tid & 63;
  int lg = lane >> 4, li = lane & 15;
  int nwg = gridDim.x;
  int sbid = (blockIdx.x & 7) * (nwg >> 3) + (blockIdx.x >> 3);
  int task = sbid * 4 + wid;
  int pairs = S >> 5;            // 64 pairs of 16-row tiles (128 tiles/head)
  int head = task / pairs;
  int pi = task - head * pairs;
  const float scale = 0.08838834764831845f;
  u16* pl = plds[wid];
  int ntiles = S >> 4;           // 128

  for (int tix = 0; tix < 2; ++tix) {
    int qt = tix ? (ntiles - 1 - pi) : pi;
    int q0 = qt << 4;

    bf16x8 aq[4];
    {
      const u16* qrow = q + (size_t)(q0 + li) * ldqk + head * HD + lg * 8;
#pragma unroll
      for (int ks = 0; ks < 4; ++ks)
        aq[ks] = *reinterpret_cast<const bf16x8*>(qrow + ks * 32);
    }

    f32x4 oacc[8] = {};
    float m_run[4], l_run[4];
#pragma unroll
    for (int r = 0; r < 4; ++r) { m_run[r] = -INFINITY; l_run[r] = 0.f; }

    int nkb = ((q0 + 15) >> 6) + 1;
    for (int kb = 0; kb < nkb; ++kb) {
      int kvbase = kb << 6;
      f32x4 sacc[4] = {};
#pragma unroll
      for (int cf = 0; cf < 4; ++cf) {
        const u16* krow = k + (size_t)(kvbase + cf * 16 + li) * ldqk + head * HD + lg * 8;
#pragma unroll
        for (int ks = 0; ks < 4; ++ks) {
          bf16x8 bk = *reinterpret_cast<const bf16x8*>(krow + ks * 32);
          sacc[cf] = __builtin_amdgcn_mfma_f32_16x16x32_bf16(aq[ks], bk, sacc[cf], 0, 0, 0);
        }
      }
      bool bnd = (kvbase + 63) > q0;
      float alpha[4];
#pragma unroll
      for (int r = 0; r < 4; ++r) {
        int row = q0 + lg * 4 + r;
#pragma unroll
        for (int cf = 0; cf < 4; ++cf) {
          float sv = sacc[cf][r] * scale;
          if (bnd && (kvbase + cf * 16 + li) > row) sv = -INFINITY;
          sacc[cf][r] = sv;
        }
        float mv = fmaxf(fmaxf(sacc[0][r], sacc[1][r]),
                         fmaxf(sacc[2][r], sacc[3][r]));
#pragma unroll
        for (int off = 1; off < 16; off <<= 1) mv = fmaxf(mv, __shfl_xor(mv, off));
        float mnew = fmaxf(m_run[r], mv);
        alpha[r] = __expf(m_run[r] - mnew);
        m_run[r] = mnew;
        float ps = 0.f;
#pragma unroll
        for (int cf = 0; cf < 4; ++cf) {
          float pv = __expf(sacc[cf][r] - mnew);
          sacc[cf][r] = pv;
          ps += pv;
        }
#pragma unroll
        for (int off = 1; off < 16; off <<= 1) ps += __shfl_xor(ps, off);
        l_run[r] = l_run[r] * alpha[r] + ps;
      }
#pragma unroll
      for (int df = 0; df < 8; ++df)
#pragma unroll
        for (int r = 0; r < 4; ++r) oacc[df][r] *= alpha[r];
      // P -> LDS (16x64 per wave, XOR-swizzled)
#pragma unroll
      for (int cf = 0; cf < 4; ++cf)
#pragma unroll
        for (int r = 0; r < 4; ++r) {
          int row = lg * 4 + r;
          int el = row * 64 + cf * 16 + li;
          pl[el ^ ((row & 7) << 3)] = f32_to_bf16(sacc[cf][r]);
        }
      asm volatile("s_waitcnt lgkmcnt(0)" ::: "memory");
      __builtin_amdgcn_sched_barrier(0);
#pragma unroll
      for (int kk = 0; kk < 2; ++kk) {
        int el = li * 64 + kk * 32 + lg * 8;
        bf16x8 pa = *reinterpret_cast<const bf16x8*>(pl + (el ^ ((li & 7) << 3)));
        const u16* vb = vt + kvbase + kk * 32 + lg * 8;
#pragma unroll
        for (int df = 0; df < 8; ++df) {
          bf16x8 bv = *reinterpret_cast<const bf16x8*>(vb + (size_t)(head * HD + df * 16 + li) * S);
          oacc[df] = __builtin_amdgcn_mfma_f32_16x16x32_bf16(pa, bv, oacc[df], 0, 0, 0);
        }
      }
    }
#pragma unroll
    for (int r = 0; r < 4; ++r) {
      float inv = 1.0f / l_run[r];
      int row = q0 + lg * 4 + r;
      u16* orow = o + (size_t)row * H_DIM + head * HD;
#pragma unroll
      for (int df = 0; df < 8; ++df)
        orow[df * 16 + li] = f32_to_bf16(oacc[df][r] * inv);
    }
  }
}

extern "C" void kernel_launch(void* const* d_in, const int* in_sizes, int n_in,
                              void* d_out, int out_size, void* d_ws, size_t ws_size,
                              hipStream_t stream) {
  (void)n_in; (void)out_size;
  const float* hidden = (const float*)d_in[0];
  const float* wq = (const float*)d_in[2];
  const float* bq = (const float*)d_in[3];
  const float* wk = (const float*)d_in[4];
  const float* bk = (const float*)d_in[5];
  const float* wv = (const float*)d_in[6];
  const float* bv = (const float*)d_in[7];
  const float* wo = (const float*)d_in[8];
  const float* bo = (const float*)d_in[9];
  const float* wg = (const float*)d_in[10];
  const float* wu = (const float*)d_in[11];
  const float* wd = (const float*)d_in[12];
  const float* ln1 = (const float*)d_in[13];
  const float* ln2 = (const float*)d_in[14];
  float* out = (float*)d_out;

  int S = in_sizes[0] / H_DIM;  // 2048
  int NQKV = 3 * H_DIM;         // 12288

  char* ws = (char*)d_ws;
  size_t off = 0;
  auto alloc = [&](size_t bytes) {
    void* p = ws + off;
    off += (bytes + 255) & ~(size_t)255;
    return p;
  };
  u16* wbuf = (u16*)alloc((size_t)FF_DIM * H_DIM * 2);  // shared weight bf16 buffer
  u16* xb   = (u16*)alloc((size_t)S * H_DIM * 2);
  u16* qkv  = (u16*)alloc((size_t)S * NQKV * 2);        // [S][12288]
  u16* vtb  = (u16*)alloc((size_t)S * H_DIM * 2);       // V^T [4096][S]
  u16* hat  = (u16*)alloc((size_t)S * H_DIM * 2);
  float* h1 = (float*)alloc((size_t)S * H_DIM * 4);
  u16* sg   = (u16*)alloc((size_t)S * FF_DIM * 2);
  u16* tb   = (u16*)alloc((size_t)S * FF_DIM * 2);
  float* bcat = (float*)alloc((size_t)NQKV * 4);
  if (off > ws_size) return;
  // split-K partials overlay qkv+vtb (both dead by O-proj / down-proj time):
  // need 2*S*H*4 = 67.11 MB; qkv(50.33) + vtb(16.78) = 67.11 MB exactly.
  float* pbuf = (float*)qkv;

  dim3 b256(256), b512(512);
  long nHH4 = (long)H_DIM * H_DIM / 4;
  long nFH4 = (long)FF_DIM * H_DIM / 4;
  int gQKV3 = (S / 256) * (NQKV / 256);      // 384
  int gO    = 2 * (S / 256) * (H_DIM / 256); // 256 (split-K=2)
  int gFF   = (S / 256) * (FF_DIM / 256);    // 448
  int gDW   = 2 * (S / 256) * (H_DIM / 256); // 256 (split-K=2)
  long n4HH = (long)S * H_DIM / 4;
  int gAttn = (NHEAD * (S / 16)) / 2 / 4;    // 512 (2048 pair-tasks / 4 waves)

  // attention block
  rmsnorm_kernel<<<S, b256, 0, stream>>>(hidden, ln1, xb);
  bias_concat_kernel<<<NQKV / 256, b256, 0, stream>>>(bq, bk, bv, bcat);
  f2b3_kernel<<<4096, b256, 0, stream>>>(wq, wk, wv, wbuf, nHH4);
  gemm256<EPI_QKV, false><<<gQKV3, b512, 0, stream>>>(xb, wbuf, qkv, bcat, nullptr,
                                                      S, NQKV, H_DIM, H_DIM);
  transpose_kernel<<<(S / 64) * (H_DIM / 64), b256, 0, stream>>>(qkv + 2 * H_DIM, vtb, S, NQKV);
  attn_kernel<<<gAttn, b256, 0, stream>>>(qkv, qkv + H_DIM, vtb, hat, S, NQKV);
  f2b_kernel<<<4096, b256, 0, stream>>>(wo, wbuf, nHH4);
  gemm256<EPI_PART, true><<<gO, b512, 0, stream>>>(hat, wbuf, pbuf, bo, nullptr,
                                                   S, H_DIM, H_DIM, H_DIM / 2);
  reduce_down<<<2048, b256, 0, stream>>>(pbuf, hidden, h1, n4HH, n4HH);

  // MLP block
  rmsnorm_kernel<<<S, b256, 0, stream>>>(h1, ln2, xb);
  f2b_kernel<<<4096, b256, 0, stream>>>(wg, wbuf, nFH4);
  gemm256<EPI_SILU, false><<<gFF, b512, 0, stream>>>(xb, wbuf, sg, nullptr, nullptr,
                                                     S, FF_DIM, H_DIM, H_DIM);
  f2b_kernel<<<4096, b256, 0, stream>>>(wu, wbuf, nFH4);
  gemm256<EPI_MUL, false><<<gFF, b512, 0, stream>>>(xb, wbuf, tb, nullptr, sg,
                                                    S, FF_DIM, H_DIM, H_DIM);
  f2b_kernel<<<4096, b256, 0, stream>>>(wd, wbuf, nFH4);
  gemm256<EPI_PART, true><<<gDW, b512, 0, stream>>>(tb, wbuf, pbuf, nullptr, nullptr,
                                                    S, H_DIM, FF_DIM, FF_DIM / 2);
  reduce_down<<<2048, b256, 0, stream>>>(pbuf, h1, out, n4HH, n4HH);
}